// Round 8
// baseline (2686.700 us; speedup 1.0000x reference)
//
#include <hip/hip_runtime.h>

// LSTM_Critic: T=512, B=256, D_IN=64, H=128. Round-21: GATE-SPLIT.
// R15-R20 established: per-SIMD MFMA-busy (1242cyc) + VALU/trans (~950) ADD
// (serialized sum + barriers = observed 2443 cyc/step) and no instruction
// reordering / wave staggering overlaps them. Remaining lever: less work per
// SIMD = more CUs. lstm_split: 64 blocks x 256 thr (1 wave/SIMD). Each tile's
// gates are split by h-half (64 dims) across a block PAIR; halves exchange
// their 16x64 fp16 h chunk per step through an L2 xbuf with agent-scope
// monotonic flags (same proven release/acquire pattern as the slab handoff).
// Pair co-located on one XCD (bids b and b+32; 32%8==0). Expected step ~1700-
// 2000 cyc -> ~360-430us. lstm_pipe reverted to best-known plain form (R18
// minus hints/stagger, 521us) as fallback when ws is too small for xbuf.

#define T_STEPS 512
#define BATCH   256
#define DIN     64
#define GROUP   16
#define NGRP    (T_STEPS / GROUP)

typedef _Float16 half8 __attribute__((ext_vector_type(8)));
typedef _Float16 half4 __attribute__((ext_vector_type(4)));
typedef float    f32x4 __attribute__((ext_vector_type(4)));

#define LOG2E  1.44269504088896f
#define LOG2E2 2.88539008177793f

// ---- ws layout (fp16 element offsets unless noted) ----
#define WH_IH0 0          // [512][64]
#define WH_HH0 32768      // [512][128]
#define WH_IH1 98304      // [512][128]
#define WH_HH1 163840     // [512][128]
// mode 2: + fp16 x + slab + flags
#define WH_X2     229376                   // 8388608 halfs
#define WH_SLAB2  8617984                  // 16777216 halfs (512*16*2048)
#define WB_FLAG2  50790400                 // byte offset, 8192 ints reserved
#define WS2_TOTAL 50823168
// mode 2S: + xbuf (2 layers x 16 tiles x 2 parity x 2 half x 1024 halfs)
#define XBUF_HOFF 25411584                 // half offset = WS2_TOTAL/2
#define WS2S_TOTAL 51085312
// mode 1: + slab + flags (x stays fp32 from input)
#define WH_SLAB1  229376
#define WB_FLAG1  34013184
#define WS1_TOTAL 34045952
// mode 0 (monolithic): optional fp16 x at WH_X2
#define WS0XH_TOTAL ((size_t)(WH_X2 + 8388608) * 2)

__global__ void prep_weights(const float* __restrict__ wih0,
                             const float* __restrict__ whh0,
                             const float* __restrict__ wih1,
                             const float* __restrict__ whh1,
                             _Float16* __restrict__ ws) {
    int idx = blockIdx.x * 256 + threadIdx.x;   // 229376 total
    float v; int row;
    if (idx < 32768)       { row = idx >> 6;             v = wih0[idx]; }
    else if (idx < 98304)  { row = (idx - 32768) >> 7;   v = whh0[idx - 32768]; }
    else if (idx < 163840) { row = (idx - 98304) >> 7;   v = wih1[idx - 98304]; }
    else                   { row = (idx - 163840) >> 7;  v = whh1[idx - 163840]; }
    float sc = ((row >> 7) == 2) ? LOG2E2 : LOG2E;
    ws[idx] = (_Float16)(v * sc);
}

__global__ void prep_state(const float* __restrict__ s, _Float16* __restrict__ d) {
    int i = (blockIdx.x * 256 + threadIdx.x) * 8;   // 8388608 elements
    f32x4 a = *(const f32x4*)(s + i);
    f32x4 b = *(const f32x4*)(s + i + 4);
    half8 h;
    h[0]=(_Float16)a[0]; h[1]=(_Float16)a[1]; h[2]=(_Float16)a[2]; h[3]=(_Float16)a[3];
    h[4]=(_Float16)b[0]; h[5]=(_Float16)b[1]; h[6]=(_Float16)b[2]; h[7]=(_Float16)b[3];
    *(half8*)(d + i) = h;
}

__device__ __forceinline__ float rcpf(float x) { return __builtin_amdgcn_rcpf(x); }
__device__ __forceinline__ float ex2(float x)  { return __builtin_amdgcn_exp2f(x); }

// legacy activations (mono path)
__device__ __forceinline__ float sig2(float y)  { return rcpf(1.0f + ex2(-y)); }
__device__ __forceinline__ float tanh2(float y2){ return 1.0f - 2.0f * rcpf(1.0f + ex2(y2)); }
__device__ __forceinline__ float tanh_c(float c){ return 1.0f - 2.0f * rcpf(1.0f + ex2(c * LOG2E2)); }

// fused activation for one row (5 exp2 + 3 rcp), exact algebra
__device__ __forceinline__ float act_row(float aI, float aF, float aG, float aO,
                                         float& ccv) {
    float Ei = ex2(-aI);
    float Ef = ex2(-aF);
    float Eg = ex2(aG);
    float Eo = ex2(-aO);
    float fg  = rcpf(1.0f + Ef);
    float igg = (Eg - 1.0f) * rcpf((1.0f + Ei) * (1.0f + Eg));
    float c   = fg * ccv + igg;
    ccv = c;
    float Ec = ex2(c * LOG2E2);
    return (Ec - 1.0f) * rcpf((1.0f + Eo) * (1.0f + Ec));
}

// LDS (halfs): hdb[2][16][128] = 4096 | woutl[128]
#define PIPE_LDS_BYTES ((4096 + 128) * 2)

// =====================  SPLIT kernel (mode 2S)  =====================
// 64 blocks x 256 thr. bid mapping (pairs co-XCD: b and b+32, 32%8==0):
// layer = (bid>>3)&1, half = bid>>5, tile = (bid&7) + 8*((bid>>4)&1).
__global__ __launch_bounds__(256, 1) void lstm_split(
        const _Float16* __restrict__ wsw,
        const float* __restrict__ b_ih0, const float* __restrict__ b_hh0,
        const float* __restrict__ b_ih1, const float* __restrict__ b_hh1,
        const float* __restrict__ w_out, const float* __restrict__ b_out,
        _Float16* __restrict__ slab, int* __restrict__ flags,
        _Float16* __restrict__ xbuf, const _Float16* __restrict__ xh,
        float* __restrict__ out) {
    extern __shared__ _Float16 lds[];
    _Float16* hdb   = lds;          // [2][16][128] swizzled, FULL h tile
    _Float16* woutl = lds + 4096;

    const int tid  = threadIdx.x;
    const int w    = tid >> 6;      // 0..3
    const int lane = tid & 63;
    const int col  = lane & 15;
    const int quad = lane >> 4;
    const int bid  = blockIdx.x;
    const int layer = (bid >> 3) & 1;         // 0 producer, 1 consumer
    const int half  = bid >> 5;               // h-half 0/1
    const int tile  = (bid & 7) + 8 * ((bid >> 4) & 1);
    const bool producer = (layer == 0);
    const int rowbase = tile * 16;
    const int j0g  = half * 64 + w * 16 + col;   // gate col within 128

    // zero hdb (both buffers): 256 thr x 16 halfs
    {
        half8 z;
        #pragma unroll
        for (int jj = 0; jj < 8; ++jj) z[jj] = (_Float16)0.0f;
        *(half8*)(hdb + tid * 16)     = z;
        *(half8*)(hdb + tid * 16 + 8) = z;
    }
    if (!producer && half == 0 && tid < 128) woutl[tid] = (_Float16)w_out[tid];

    // resident input-side B-frags + scaled biases
    half8 wresf[4][4];
    float bias[4];
    #pragma unroll
    for (int nt = 0; nt < 4; ++nt) {
        int j = nt * 128 + j0g;
        float sc = (nt == 2) ? LOG2E2 : LOG2E;
        if (producer) {
            #pragma unroll
            for (int kt = 0; kt < 2; ++kt)
                wresf[nt][kt] = *(const half8*)(wsw + WH_IH0 + j * 64 + kt * 32 + quad * 8);
            bias[nt] = (b_ih0[j] + b_hh0[j]) * sc;
        } else {
            #pragma unroll
            for (int kt = 0; kt < 4; ++kt)
                wresf[nt][kt] = *(const half8*)(wsw + WH_IH1 + j * 128 + kt * 32 + quad * 8);
            bias[nt] = (b_ih1[j] + b_hh1[j]) * sc;
        }
    }
    const float bout = b_out[0];

    // resident recurrent B-frags from global
    half8 wpf[4][4];
    {
        const _Float16* wrg = wsw + (producer ? WH_HH0 : WH_HH1);
        #pragma unroll
        for (int kt = 0; kt < 4; ++kt)
            #pragma unroll
            for (int nt = 0; nt < 4; ++nt)
                wpf[kt][nt] = *(const half8*)(wrg + (nt * 128 + j0g) * 128 + kt * 32 + quad * 8);
    }
    #pragma unroll
    for (int kt = 0; kt < 4; ++kt)
        #pragma unroll
        for (int nt = 0; nt < 4; ++nt)
            asm volatile("" : "+v"(wpf[kt][nt]));

    // addressing: A-frags over FULL K, swizzle addr(row,c)=row*128+((c>>3 ^ row)*8)+(c&7)
    int hoff[4], w0off[4];
    #pragma unroll
    for (int kt = 0; kt < 4; ++kt)
        hoff[kt] = col * 128 + (((kt * 4 + quad) ^ col) * 8);
    {
        const int cg = j0g >> 3, c7 = j0g & 7;
        #pragma unroll
        for (int i = 0; i < 4; ++i) {
            int row = quad * 4 + i;
            w0off[i] = row * 128 + ((cg ^ row) * 8) + c7;
        }
    }
    // exchange / slab-copy addressing
    const int xrow = tid >> 4;              // 0..15
    const int xc4  = (tid & 15) * 4;        // 0..60
    const int cown = half * 64 + xc4;
    const int ldsown  = xrow * 128 + (((cown >> 3) ^ xrow) * 8) + (cown & 7);
    const int cpart = (half ^ 1) * 64 + xc4;
    const int ldspart = xrow * 128 + (((cpart >> 3) ^ xrow) * 8) + (cpart & 7);
    const int xsc = w * 16 + col;           // within-half col for scatter store
    int* xfl = flags + 2048;                // xchg flags region

    float cc[4] = {0.f, 0.f, 0.f, 0.f};
    __syncthreads();

    if (producer) {
        const _Float16* xph = xh + (size_t)(rowbase + col) * DIN + quad * 8;
        half8 bx0, bx1;
        f32x4 accI[4];
        {
            half8 a0  = *(const half8*)(xph);
            half8 a1v = *(const half8*)(xph + 32);
            #pragma unroll
            for (int nt = 0; nt < 4; ++nt) {
                f32x4 b = {bias[nt], bias[nt], bias[nt], bias[nt]};
                accI[nt] = b;
            }
            #pragma unroll
            for (int nt = 0; nt < 4; ++nt)
                accI[nt] = __builtin_amdgcn_mfma_f32_16x16x32_f16(a0, wresf[nt][0], accI[nt], 0, 0, 0);
            #pragma unroll
            for (int nt = 0; nt < 4; ++nt)
                accI[nt] = __builtin_amdgcn_mfma_f32_16x16x32_f16(a1v, wresf[nt][1], accI[nt], 0, 0, 0);
            bx0 = *(const half8*)(xph + BATCH * DIN);
            bx1 = *(const half8*)(xph + BATCH * DIN + 32);
        }

        #pragma unroll 1
        for (int t = 0; t < T_STEPS; ++t) {
            const int pbo = (t & 1) * 2048, cbo = pbo ^ 2048;
            const int lt = t & (GROUP - 1);
            __syncthreads();   // h(t-1) full (own act + partner xchg) visible

            if (t > 0) {   // slab copy own half of h(t-1), coalesced-ish
                half4 hv = *(const half4*)(hdb + pbo + ldsown);
                *(half4*)(slab + (size_t)((t - 1) * 16 + tile) * 2048 + xrow * 128 + cown) = hv;
            }
            if (lt == 1 && t > 16 && tid == 0)
                __hip_atomic_store(flags + ((t >> 4) - 1) * 32 + tile * 2 + half, t >> 4,
                                   __ATOMIC_RELEASE, __HIP_MEMORY_SCOPE_AGENT);

            half8 ah[4];
            #pragma unroll
            for (int kt = 0; kt < 4; ++kt)
                ah[kt] = *(const half8*)(hdb + pbo + hoff[kt]);
            #pragma unroll
            for (int kt = 0; kt < 4; ++kt)
                #pragma unroll
                for (int nt = 0; nt < 4; ++nt)
                    accI[nt] = __builtin_amdgcn_mfma_f32_16x16x32_f16(ah[kt], wpf[kt][nt], accI[nt], 0, 0, 0);

            // prefetch x(t+2)
            half8 fx0, fx1;
            {
                int tn2 = (t + 2 < T_STEPS) ? t + 2 : T_STEPS - 1;
                const _Float16* xq = xph + (size_t)tn2 * (BATCH * DIN);
                fx0 = *(const half8*)(xq);
                fx1 = *(const half8*)(xq + 32);
            }
            // tail accN = bias + x(t+1)-part
            f32x4 accN[4];
            #pragma unroll
            for (int nt = 0; nt < 4; ++nt) {
                f32x4 b = {bias[nt], bias[nt], bias[nt], bias[nt]};
                accN[nt] = b;
            }
            #pragma unroll
            for (int nt = 0; nt < 4; ++nt)
                accN[nt] = __builtin_amdgcn_mfma_f32_16x16x32_f16(bx0, wresf[nt][0], accN[nt], 0, 0, 0);
            #pragma unroll
            for (int nt = 0; nt < 4; ++nt)
                accN[nt] = __builtin_amdgcn_mfma_f32_16x16x32_f16(bx1, wresf[nt][1], accN[nt], 0, 0, 0);

            // act -> LDS own half + xbuf scatter
            const int slot = ((0 * 16 + tile) * 2 + (t & 1)) * 2 + half;
            _Float16* xb = xbuf + (size_t)slot * 1024;
            #pragma unroll
            for (int i = 0; i < 4; ++i) {
                float hval = act_row(accI[0][i], accI[1][i], accI[2][i], accI[3][i], cc[i]);
                _Float16 hf = (_Float16)hval;
                hdb[cbo + w0off[i]] = hf;
                xb[(quad * 4 + i) * 64 + xsc] = hf;
            }
            __syncthreads();   // per-thread vmcnt drained -> xbuf stores agent-visible
            if (tid == 0)
                __hip_atomic_store(xfl + slot, (t >> 1) + 1,
                                   __ATOMIC_RELEASE, __HIP_MEMORY_SCOPE_AGENT);
            {
                const int pslot = ((0 * 16 + tile) * 2 + (t & 1)) * 2 + (half ^ 1);
                const int want = (t >> 1) + 1;
                while (__hip_atomic_load(xfl + pslot, __ATOMIC_ACQUIRE,
                                         __HIP_MEMORY_SCOPE_AGENT) < want)
                    __builtin_amdgcn_s_sleep(1);
                const _Float16* pxb = xbuf + (size_t)pslot * 1024;
                half4 ph = *(const half4*)(pxb + xrow * 64 + xc4);
                *(half4*)(hdb + cbo + ldspart) = ph;
            }
            #pragma unroll
            for (int nt = 0; nt < 4; ++nt) accI[nt] = accN[nt];
            bx0 = fx0; bx1 = fx1;
        }
        __syncthreads();
        {   // h(T-1) is in buffer cbo(511) = 0
            half4 hv = *(const half4*)(hdb + 0 + ldsown);
            *(half4*)(slab + (size_t)((T_STEPS - 1) * 16 + tile) * 2048 + xrow * 128 + cown) = hv;
        }
        __syncthreads();
        if (tid == 0)
            __hip_atomic_store(flags + (NGRP - 1) * 32 + tile * 2 + half, NGRP,
                               __ATOMIC_RELEASE, __HIP_MEMORY_SCOPE_AGENT);
    } else {
        // ---------- layer-1 consumer ----------
        if (tid == 0) {
            while (__hip_atomic_load(flags + tile * 2, __ATOMIC_ACQUIRE,
                                     __HIP_MEMORY_SCOPE_AGENT) < 1 ||
                   __hip_atomic_load(flags + tile * 2 + 1, __ATOMIC_ACQUIRE,
                                     __HIP_MEMORY_SCOPE_AGENT) < 1)
                __builtin_amdgcn_s_sleep(1);
        }
        __syncthreads();

        half8 uA[4];
        f32x4 accI[4];
        {
            const _Float16* s0 = slab + (size_t)tile * 2048;
            half8 cA[4];
            #pragma unroll
            for (int kt = 0; kt < 4; ++kt)
                cA[kt] = *(const half8*)(s0 + col * 128 + kt * 32 + quad * 8);
            #pragma unroll
            for (int nt = 0; nt < 4; ++nt) {
                f32x4 b = {bias[nt], bias[nt], bias[nt], bias[nt]};
                accI[nt] = b;
            }
            #pragma unroll
            for (int kt = 0; kt < 4; ++kt)
                #pragma unroll
                for (int nt = 0; nt < 4; ++nt)
                    accI[nt] = __builtin_amdgcn_mfma_f32_16x16x32_f16(cA[kt], wresf[nt][kt], accI[nt], 0, 0, 0);
            const _Float16* s1 = slab + (size_t)(16 + tile) * 2048;
            #pragma unroll
            for (int kt = 0; kt < 4; ++kt)
                uA[kt] = *(const half8*)(s1 + col * 128 + kt * 32 + quad * 8);
        }

        #pragma unroll 1
        for (int t = 0; t < T_STEPS; ++t) {
            const int pbo = (t & 1) * 2048, cbo = pbo ^ 2048;
            const int lt = t & (GROUP - 1);
            __syncthreads();   // h1(t-1) full visible

            half8 a1[4];
            #pragma unroll
            for (int kt = 0; kt < 4; ++kt)
                a1[kt] = *(const half8*)(hdb + pbo + hoff[kt]);
            #pragma unroll
            for (int kt = 0; kt < 4; ++kt)
                #pragma unroll
                for (int nt = 0; nt < 4; ++nt)
                    accI[nt] = __builtin_amdgcn_mfma_f32_16x16x32_f16(a1[kt], wpf[kt][nt], accI[nt], 0, 0, 0);

            if (lt == 12 && tid == 0) {
                int g1 = (t >> 4) + 1;
                if (g1 < NGRP) {
                    while (__hip_atomic_load(flags + g1 * 32 + tile * 2, __ATOMIC_ACQUIRE,
                                             __HIP_MEMORY_SCOPE_AGENT) < g1 + 1 ||
                           __hip_atomic_load(flags + g1 * 32 + tile * 2 + 1, __ATOMIC_ACQUIRE,
                                             __HIP_MEMORY_SCOPE_AGENT) < g1 + 1)
                        __builtin_amdgcn_s_sleep(1);
                }
            }

            half8 fA[4];
            {
                int tn2 = (t + 2 < T_STEPS) ? t + 2 : T_STEPS - 1;
                const _Float16* sq = slab + (size_t)(tn2 * 16 + tile) * 2048;
                #pragma unroll
                for (int kt = 0; kt < 4; ++kt)
                    fA[kt] = *(const half8*)(sq + col * 128 + kt * 32 + quad * 8);
            }

            f32x4 accN[4];
            #pragma unroll
            for (int nt = 0; nt < 4; ++nt) {
                f32x4 b = {bias[nt], bias[nt], bias[nt], bias[nt]};
                accN[nt] = b;
            }
            #pragma unroll
            for (int kt = 0; kt < 4; ++kt)
                #pragma unroll
                for (int nt = 0; nt < 4; ++nt)
                    accN[nt] = __builtin_amdgcn_mfma_f32_16x16x32_f16(uA[kt], wresf[nt][kt], accN[nt], 0, 0, 0);

            const int slot = ((1 * 16 + tile) * 2 + (t & 1)) * 2 + half;
            _Float16* xb = xbuf + (size_t)slot * 1024;
            #pragma unroll
            for (int i = 0; i < 4; ++i) {
                float hval = act_row(accI[0][i], accI[1][i], accI[2][i], accI[3][i], cc[i]);
                _Float16 hf = (_Float16)hval;
                hdb[cbo + w0off[i]] = hf;
                xb[(quad * 4 + i) * 64 + xsc] = hf;
            }

            // value head for t-1 on half-0 block, wave 3 (h1(t-1) = pbo buffer)
            if (half == 0 && w == 3) {
                f32x4 vh = {0.f, 0.f, 0.f, 0.f};
                #pragma unroll
                for (int kt = 0; kt < 4; ++kt) {
                    half8 av = *(const half8*)(hdb + pbo + hoff[kt]);
                    half8 bw = *(const half8*)(woutl + kt * 32 + quad * 8);
                    vh = __builtin_amdgcn_mfma_f32_16x16x32_f16(av, bw, vh, 0, 0, 0);
                }
                if (t > 0 && col == 0) {
                    f32x4 vo = {vh[0] + bout, vh[1] + bout, vh[2] + bout, vh[3] + bout};
                    *(f32x4*)(out + (size_t)(t - 1) * BATCH + rowbase + quad * 4) = vo;
                }
            }

            __syncthreads();   // xbuf stores drained per-thread
            if (tid == 0)
                __hip_atomic_store(xfl + slot, (t >> 1) + 1,
                                   __ATOMIC_RELEASE, __HIP_MEMORY_SCOPE_AGENT);
            {
                const int pslot = ((1 * 16 + tile) * 2 + (t & 1)) * 2 + (half ^ 1);
                const int want = (t >> 1) + 1;
                while (__hip_atomic_load(xfl + pslot, __ATOMIC_ACQUIRE,
                                         __HIP_MEMORY_SCOPE_AGENT) < want)
                    __builtin_amdgcn_s_sleep(1);
                const _Float16* pxb = xbuf + (size_t)pslot * 1024;
                half4 ph = *(const half4*)(pxb + xrow * 64 + xc4);
                *(half4*)(hdb + cbo + ldspart) = ph;
            }
            #pragma unroll
            for (int nt = 0; nt < 4; ++nt) accI[nt] = accN[nt];
            #pragma unroll
            for (int kt = 0; kt < 4; ++kt) uA[kt] = fA[kt];
        }
        __syncthreads();
        if (half == 0 && w == 3) {   // head for t = T-1; h1(T-1) in buffer 0
            f32x4 vh = {0.f, 0.f, 0.f, 0.f};
            #pragma unroll
            for (int kt = 0; kt < 4; ++kt) {
                half8 av = *(const half8*)(hdb + 0 + hoff[kt]);
                half8 bw = *(const half8*)(woutl + kt * 32 + quad * 8);
                vh = __builtin_amdgcn_mfma_f32_16x16x32_f16(av, bw, vh, 0, 0, 0);
            }
            if (col == 0) {
                f32x4 vo = {vh[0] + bout, vh[1] + bout, vh[2] + bout, vh[3] + bout};
                *(f32x4*)(out + (size_t)(T_STEPS - 1) * BATCH + rowbase + quad * 4) = vo;
            }
        }
    }
}

// =====================  pipelined kernel (fallback, R17/R18-plain)  =========
template<bool XH>
__global__ __launch_bounds__(512, 1) void lstm_pipe(
        const float* __restrict__ state32, const _Float16* __restrict__ wsw,
        const float* __restrict__ b_ih0, const float* __restrict__ b_hh0,
        const float* __restrict__ b_ih1, const float* __restrict__ b_hh1,
        const float* __restrict__ w_out, const float* __restrict__ b_out,
        _Float16* __restrict__ slab, int* __restrict__ flags,
        const _Float16* __restrict__ xh, float* __restrict__ out) {
    extern __shared__ _Float16 lds[];
    _Float16* hdb   = lds;
    _Float16* woutl = lds + 4096;

    const int tid  = threadIdx.x;
    const int w    = tid >> 6;
    const int lane = tid & 63;
    const int col  = lane & 15;
    const int quad = lane >> 4;
    const bool producer = blockIdx.x < 16;
    const int tile = blockIdx.x & 15;
    const int rowbase = tile * 16;
    const int j0 = w * 16 + col;

    {
        half8 z;
        #pragma unroll
        for (int jj = 0; jj < 8; ++jj) z[jj] = (_Float16)0.0f;
        *(half8*)(hdb + tid * 8) = z;
    }
    if (!producer && tid < 128) woutl[tid] = (_Float16)w_out[tid];

    half8 wresf[4][4];
    float bias[4];
    #pragma unroll
    for (int nt = 0; nt < 4; ++nt) {
        int j = nt * 128 + j0;
        float sc = (nt == 2) ? LOG2E2 : LOG2E;
        if (producer) {
            #pragma unroll
            for (int kt = 0; kt < 2; ++kt)
                wresf[nt][kt] = *(const half8*)(wsw + WH_IH0 + j * 64 + kt * 32 + quad * 8);
            bias[nt] = (b_ih0[j] + b_hh0[j]) * sc;
        } else {
            #pragma unroll
            for (int kt = 0; kt < 4; ++kt)
                wresf[nt][kt] = *(const half8*)(wsw + WH_IH1 + j * 128 + kt * 32 + quad * 8);
            bias[nt] = (b_ih1[j] + b_hh1[j]) * sc;
        }
    }
    const float bout = b_out[0];

    half8 wpf[4][4];
    {
        const _Float16* wrg = wsw + (producer ? WH_HH0 : WH_HH1);
        #pragma unroll
        for (int kt = 0; kt < 4; ++kt)
            #pragma unroll
            for (int nt = 0; nt < 4; ++nt)
                wpf[kt][nt] = *(const half8*)(wrg + (nt * 128 + j0) * 128 + kt * 32 + quad * 8);
    }
    #pragma unroll
    for (int kt = 0; kt < 4; ++kt)
        #pragma unroll
        for (int nt = 0; nt < 4; ++nt)
            asm volatile("" : "+v"(wpf[kt][nt]));

    int swz[4], hoff[4], w0off[4];
    #pragma unroll
    for (int kt = 0; kt < 4; ++kt) {
        swz[kt]  = ((kt * 4 + quad) ^ col) * 8;
        hoff[kt] = col * 128 + swz[kt];
    }
    #pragma unroll
    for (int i = 0; i < 4; ++i) {
        int row = quad * 4 + i;
        w0off[i] = row * 128 + (((2 * w + (col >> 3)) ^ row) * 8) + (col & 7);
    }
    float cc[4] = {0.f, 0.f, 0.f, 0.f};

    const int cr   = tid >> 5;
    const int cc0  = (tid & 31) * 4;
    const int cprd = cr * 128 + (((cc0 >> 3) ^ cr) * 8) + (cc0 & 7);

    __syncthreads();

    if (producer) {
        const _Float16* xph = xh + (size_t)(rowbase + col) * DIN + quad * 8;
        const float*    xpf = state32 + (size_t)(rowbase + col) * DIN + quad * 8;
        half8 bx0, bx1;
        f32x4 bf0, bf1, bf2, bf3;
        f32x4 accI[4];
        {
            half8 a0, a1v;
            if constexpr (XH) {
                a0  = *(const half8*)(xph);
                a1v = *(const half8*)(xph + 32);
            } else {
                f32x4 t0 = *(const f32x4*)(xpf),      t1 = *(const f32x4*)(xpf + 4);
                f32x4 t2 = *(const f32x4*)(xpf + 32), t3 = *(const f32x4*)(xpf + 36);
                #pragma unroll
                for (int jj = 0; jj < 4; ++jj) {
                    a0[jj]  = (_Float16)t0[jj]; a0[jj+4]  = (_Float16)t1[jj];
                    a1v[jj] = (_Float16)t2[jj]; a1v[jj+4] = (_Float16)t3[jj];
                }
            }
            #pragma unroll
            for (int nt = 0; nt < 4; ++nt) {
                f32x4 b = {bias[nt], bias[nt], bias[nt], bias[nt]};
                accI[nt] = b;
            }
            #pragma unroll
            for (int nt = 0; nt < 4; ++nt)
                accI[nt] = __builtin_amdgcn_mfma_f32_16x16x32_f16(a0, wresf[nt][0], accI[nt], 0, 0, 0);
            #pragma unroll
            for (int nt = 0; nt < 4; ++nt)
                accI[nt] = __builtin_amdgcn_mfma_f32_16x16x32_f16(a1v, wresf[nt][1], accI[nt], 0, 0, 0);
            if constexpr (XH) {
                bx0 = *(const half8*)(xph + BATCH * DIN);
                bx1 = *(const half8*)(xph + BATCH * DIN + 32);
            } else {
                bf0 = *(const f32x4*)(xpf + BATCH * DIN);
                bf1 = *(const f32x4*)(xpf + BATCH * DIN + 4);
                bf2 = *(const f32x4*)(xpf + BATCH * DIN + 32);
                bf3 = *(const f32x4*)(xpf + BATCH * DIN + 36);
            }
        }

        #pragma unroll 2
        for (int t = 0; t < T_STEPS; ++t) {
            const int pbo = (t & 1) * 2048, cbo = pbo ^ 2048;
            const int lt = t & (GROUP - 1);
            __syncthreads();

            if (t > 0) {
                half4 hv = *(const half4*)(hdb + pbo + cprd);
                *(half4*)(slab + (size_t)((t - 1) * 16 + tile) * 2048 + tid * 4) = hv;
            }
            if (lt == 1 && t > 16 && tid == 0)
                __hip_atomic_store(flags + ((t >> 4) - 1) * 16 + tile, t >> 4,
                                   __ATOMIC_RELEASE, __HIP_MEMORY_SCOPE_AGENT);

            half8 ah[4];
            #pragma unroll
            for (int kt = 0; kt < 4; ++kt)
                ah[kt] = *(const half8*)(hdb + pbo + hoff[kt]);
            #pragma unroll
            for (int kt = 0; kt < 4; ++kt)
                #pragma unroll
                for (int nt = 0; nt < 4; ++nt)
                    accI[nt] = __builtin_amdgcn_mfma_f32_16x16x32_f16(ah[kt], wpf[kt][nt], accI[nt], 0, 0, 0);

            half8 fx0, fx1;
            f32x4 ff0, ff1, ff2, ff3;
            {
                int tn2 = (t + 2 < T_STEPS) ? t + 2 : T_STEPS - 1;
                if constexpr (XH) {
                    const _Float16* xq = xph + (size_t)tn2 * (BATCH * DIN);
                    fx0 = *(const half8*)(xq);
                    fx1 = *(const half8*)(xq + 32);
                } else {
                    const float* xq = xpf + (size_t)tn2 * (BATCH * DIN);
                    ff0 = *(const f32x4*)(xq);      ff1 = *(const f32x4*)(xq + 4);
                    ff2 = *(const f32x4*)(xq + 32); ff3 = *(const f32x4*)(xq + 36);
                }
            }

            half8 cx0, cx1;
            if constexpr (XH) { cx0 = bx0; cx1 = bx1; }
            else {
                #pragma unroll
                for (int jj = 0; jj < 4; ++jj) {
                    cx0[jj] = (_Float16)bf0[jj]; cx0[jj+4] = (_Float16)bf1[jj];
                    cx1[jj] = (_Float16)bf2[jj]; cx1[jj+4] = (_Float16)bf3[jj];
                }
            }
            f32x4 accN[4];
            #pragma unroll
            for (int nt = 0; nt < 4; ++nt) {
                f32x4 b = {bias[nt], bias[nt], bias[nt], bias[nt]};
                accN[nt] = b;
            }
            #pragma unroll
            for (int nt = 0; nt < 4; ++nt)
                accN[nt] = __builtin_amdgcn_mfma_f32_16x16x32_f16(cx0, wresf[nt][0], accN[nt], 0, 0, 0);
            #pragma unroll
            for (int nt = 0; nt < 4; ++nt)
                accN[nt] = __builtin_amdgcn_mfma_f32_16x16x32_f16(cx1, wresf[nt][1], accN[nt], 0, 0, 0);

            #pragma unroll
            for (int i = 0; i < 4; ++i) {
                float hval = act_row(accI[0][i], accI[1][i], accI[2][i], accI[3][i], cc[i]);
                hdb[cbo + w0off[i]] = (_Float16)hval;
            }

            #pragma unroll
            for (int nt = 0; nt < 4; ++nt) accI[nt] = accN[nt];
            if constexpr (XH) { bx0 = fx0; bx1 = fx1; }
            else { bf0 = ff0; bf1 = ff1; bf2 = ff2; bf3 = ff3; }
        }
        __syncthreads();
        {
            half4 hv = *(const half4*)(hdb + 0 + cprd);
            *(half4*)(slab + (size_t)((T_STEPS - 1) * 16 + tile) * 2048 + tid * 4) = hv;
        }
        __syncthreads();
        if (tid == 0)
            __hip_atomic_store(flags + (NGRP - 1) * 16 + tile, NGRP,
                               __ATOMIC_RELEASE, __HIP_MEMORY_SCOPE_AGENT);
    } else {
        if (tid == 0) {
            while (__hip_atomic_load(flags + tile, __ATOMIC_ACQUIRE,
                                     __HIP_MEMORY_SCOPE_AGENT) < 1)
                __builtin_amdgcn_s_sleep(1);
        }
        __syncthreads();

        half8 uA[4];
        f32x4 accI[4];
        {
            const _Float16* s0 = slab + (size_t)tile * 2048;
            half8 cA[4];
            #pragma unroll
            for (int kt = 0; kt < 4; ++kt)
                cA[kt] = *(const half8*)(s0 + col * 128 + kt * 32 + quad * 8);
            #pragma unroll
            for (int nt = 0; nt < 4; ++nt) {
                f32x4 b = {bias[nt], bias[nt], bias[nt], bias[nt]};
                accI[nt] = b;
            }
            #pragma unroll
            for (int kt = 0; kt < 4; ++kt)
                #pragma unroll
                for (int nt = 0; nt < 4; ++nt)
                    accI[nt] = __builtin_amdgcn_mfma_f32_16x16x32_f16(cA[kt], wresf[nt][kt], accI[nt], 0, 0, 0);
            const _Float16* s1 = slab + (size_t)(16 + tile) * 2048;
            #pragma unroll
            for (int kt = 0; kt < 4; ++kt)
                uA[kt] = *(const half8*)(s1 + col * 128 + kt * 32 + quad * 8);
        }

        #pragma unroll 2
        for (int t = 0; t < T_STEPS; ++t) {
            const int pbo = (t & 1) * 2048, cbo = pbo ^ 2048;
            const int lt = t & (GROUP - 1);
            __syncthreads();

            half8 a1[4];
            #pragma unroll
            for (int kt = 0; kt < 4; ++kt)
                a1[kt] = *(const half8*)(hdb + pbo + hoff[kt]);
            #pragma unroll
            for (int kt = 0; kt < 4; ++kt)
                #pragma unroll
                for (int nt = 0; nt < 4; ++nt)
                    accI[nt] = __builtin_amdgcn_mfma_f32_16x16x32_f16(a1[kt], wpf[kt][nt], accI[nt], 0, 0, 0);

            if (lt == 12 && tid == 0) {
                int g1 = (t >> 4) + 1;
                if (g1 < NGRP) {
                    while (__hip_atomic_load(flags + g1 * 16 + tile, __ATOMIC_ACQUIRE,
                                             __HIP_MEMORY_SCOPE_AGENT) < g1 + 1)
                        __builtin_amdgcn_s_sleep(1);
                }
            }

            half8 fA[4];
            {
                int tn2 = (t + 2 < T_STEPS) ? t + 2 : T_STEPS - 1;
                const _Float16* sq = slab + (size_t)(tn2 * 16 + tile) * 2048;
                #pragma unroll
                for (int kt = 0; kt < 4; ++kt)
                    fA[kt] = *(const half8*)(sq + col * 128 + kt * 32 + quad * 8);
            }

            f32x4 accN[4];
            #pragma unroll
            for (int nt = 0; nt < 4; ++nt) {
                f32x4 b = {bias[nt], bias[nt], bias[nt], bias[nt]};
                accN[nt] = b;
            }
            #pragma unroll
            for (int kt = 0; kt < 4; ++kt)
                #pragma unroll
                for (int nt = 0; nt < 4; ++nt)
                    accN[nt] = __builtin_amdgcn_mfma_f32_16x16x32_f16(uA[kt], wresf[nt][kt], accN[nt], 0, 0, 0);

            #pragma unroll
            for (int i = 0; i < 4; ++i) {
                float hval = act_row(accI[0][i], accI[1][i], accI[2][i], accI[3][i], cc[i]);
                hdb[cbo + w0off[i]] = (_Float16)hval;
            }

            if (w == 7) {
                f32x4 vh = {0.f, 0.f, 0.f, 0.f};
                #pragma unroll
                for (int kt = 0; kt < 4; ++kt) {
                    half8 av = *(const half8*)(hdb + pbo + hoff[kt]);
                    half8 bw = *(const half8*)(woutl + kt * 32 + quad * 8);
                    vh = __builtin_amdgcn_mfma_f32_16x16x32_f16(av, bw, vh, 0, 0, 0);
                }
                if (t > 0 && col == 0) {
                    f32x4 vo = {vh[0] + bout, vh[1] + bout, vh[2] + bout, vh[3] + bout};
                    *(f32x4*)(out + (size_t)(t - 1) * BATCH + rowbase + quad * 4) = vo;
                }
            }

            #pragma unroll
            for (int nt = 0; nt < 4; ++nt) accI[nt] = accN[nt];
            #pragma unroll
            for (int kt = 0; kt < 4; ++kt) uA[kt] = fA[kt];
        }
        __syncthreads();
        if (w == 7) {
            const int fbo = (((T_STEPS - 1) & 1) ^ 1) * 2048;
            f32x4 vh = {0.f, 0.f, 0.f, 0.f};
            #pragma unroll
            for (int kt = 0; kt < 4; ++kt) {
                half8 av = *(const half8*)(hdb + fbo + hoff[kt]);
                half8 bw = *(const half8*)(woutl + kt * 32 + quad * 8);
                vh = __builtin_amdgcn_mfma_f32_16x16x32_f16(av, bw, vh, 0, 0, 0);
            }
            if (col == 0) {
                f32x4 vo = {vh[0] + bout, vh[1] + bout, vh[2] + bout, vh[3] + bout};
                *(f32x4*)(out + (size_t)(T_STEPS - 1) * BATCH + rowbase + quad * 4) = vo;
            }
        }
    }
}

// =====================  monolithic fallback  =====
#define MONO_LDS_BYTES ((73728 + 128) * 2)

template<bool XH>
__global__ __launch_bounds__(512, 2) void lstm_mono(
        const float* __restrict__ state32, const _Float16* __restrict__ wsw,
        const float* __restrict__ b_ih0, const float* __restrict__ b_hh0,
        const float* __restrict__ b_ih1, const float* __restrict__ b_hh1,
        const float* __restrict__ w_out, const float* __restrict__ b_out,
        float* __restrict__ out) {
    extern __shared__ _Float16 lds[];
    _Float16* whh1  = lds;
    _Float16* h0b   = lds + 65536;
    _Float16* h1b   = lds + 69632;
    _Float16* woutl = lds + 73728;

    const int tid  = threadIdx.x;
    const int w    = tid >> 6;
    const int lane = tid & 63;
    const int col  = lane & 15;
    const int quad = lane >> 4;
    const int rowbase = blockIdx.x * 16;
    const int j0 = w * 16 + col;

    const _Float16* whh1g = wsw + WH_HH1;
    #pragma unroll
    for (int it = 0; it < 16; ++it) {
        int flat = (it * 512 + tid) * 8;
        int r = flat >> 7, chunk = (flat >> 3) & 15;
        *(half8*)(whh1 + r * 128 + ((chunk ^ (r & 15)) * 8)) = *(const half8*)(whh1g + flat);
    }
    {
        half8 z;
        #pragma unroll
        for (int jj = 0; jj < 8; ++jj) z[jj] = (_Float16)0.0f;
        for (int i = tid * 8; i < 8192; i += 4096) *(half8*)(h0b + i) = z;
    }
    if (tid < 128) woutl[tid] = (_Float16)w_out[tid];

    half8 whh0f[4][4], wih1f[4][4];
    float bias0[4], bias1[4];
    #pragma unroll
    for (int nt = 0; nt < 4; ++nt) {
        int j = nt * 128 + j0;
        float sc = (nt == 2) ? LOG2E2 : LOG2E;
        #pragma unroll
        for (int kt = 0; kt < 4; ++kt) {
            whh0f[nt][kt] = *(const half8*)(wsw + WH_HH0 + j * 128 + kt * 32 + quad * 8);
            wih1f[nt][kt] = *(const half8*)(wsw + WH_IH1 + j * 128 + kt * 32 + quad * 8);
        }
        bias0[nt] = (b_ih0[j] + b_hh0[j]) * sc;
        bias1[nt] = (b_ih1[j] + b_hh1[j]) * sc;
    }
    const float bout = b_out[0];

    int swz[4], hoff[4], w0off[4];
    #pragma unroll
    for (int kt = 0; kt < 4; ++kt) {
        swz[kt]  = ((kt * 4 + quad) ^ col) * 8;
        hoff[kt] = col * 128 + swz[kt];
    }
    #pragma unroll
    for (int i = 0; i < 4; ++i) {
        int row = quad * 4 + i;
        w0off[i] = row * 128 + (((2 * w + (col >> 3)) ^ row) * 8) + (col & 7);
    }
    float c0[4] = {0.f,0.f,0.f,0.f}, c1[4] = {0.f,0.f,0.f,0.f};

    const _Float16* xph = wsw + WH_X2 + (size_t)(rowbase + col) * DIN + quad * 8;
    const float*    xpf = state32 + (size_t)(rowbase + col) * DIN + quad * 8;
    half8 nxh0, nxh1;
    f32x4 nxf0, nxf1, nxf2, nxf3;
    if constexpr (XH) {
        nxh0 = *(const half8*)(xph); nxh1 = *(const half8*)(xph + 32);
    } else {
        nxf0 = *(const f32x4*)(xpf);      nxf1 = *(const f32x4*)(xpf + 4);
        nxf2 = *(const f32x4*)(xpf + 32); nxf3 = *(const f32x4*)(xpf + 36);
    }
    __syncthreads();
    const _Float16* wih0g = wsw + WH_IH0;

    #pragma unroll 1
    for (int t = 0; t < T_STEPS; ++t) {
        const int pbo = (t & 1) * 2048, cbo = pbo ^ 2048;
        half8 ax0, ax1;
        if constexpr (XH) { ax0 = nxh0; ax1 = nxh1; }
        else {
            #pragma unroll
            for (int jj = 0; jj < 4; ++jj) {
                ax0[jj]   = (_Float16)nxf0[jj]; ax0[jj+4] = (_Float16)nxf1[jj];
                ax1[jj]   = (_Float16)nxf2[jj]; ax1[jj+4] = (_Float16)nxf3[jj];
            }
        }
        half8 wif[4][2];
        #pragma unroll
        for (int nt = 0; nt < 4; ++nt)
            #pragma unroll
            for (int kt = 0; kt < 2; ++kt)
                wif[nt][kt] = *(const half8*)(wih0g + (nt * 128 + j0) * 64 + kt * 32 + quad * 8);
        half8 ah[4];
        #pragma unroll
        for (int kt = 0; kt < 4; ++kt)
            ah[kt] = *(const half8*)(h0b + pbo + hoff[kt]);

        f32x4 acc[4];
        #pragma unroll
        for (int nt = 0; nt < 4; ++nt) {
            f32x4 b = {bias0[nt], bias0[nt], bias0[nt], bias0[nt]};
            acc[nt] = b;
        }
        #pragma unroll
        for (int kt = 0; kt < 4; ++kt)
            #pragma unroll
            for (int nt = 0; nt < 4; ++nt)
                acc[nt] = __builtin_amdgcn_mfma_f32_16x16x32_f16(ah[kt], whh0f[nt][kt], acc[nt], 0, 0, 0);
        #pragma unroll
        for (int kt = 0; kt < 2; ++kt) {
            half8 axk = kt ? ax1 : ax0;
            #pragma unroll
            for (int nt = 0; nt < 4; ++nt)
                acc[nt] = __builtin_amdgcn_mfma_f32_16x16x32_f16(axk, wif[nt][kt], acc[nt], 0, 0, 0);
        }
        {
            int tn = (t + 1 < T_STEPS) ? t + 1 : t;
            if constexpr (XH) {
                const _Float16* xq = xph + (size_t)tn * (BATCH * DIN);
                nxh0 = *(const half8*)(xq); nxh1 = *(const half8*)(xq + 32);
            } else {
                const float* xq = xpf + (size_t)tn * (BATCH * DIN);
                nxf0 = *(const f32x4*)(xq);      nxf1 = *(const f32x4*)(xq + 4);
                nxf2 = *(const f32x4*)(xq + 32); nxf3 = *(const f32x4*)(xq + 36);
            }
        }
        #pragma unroll
        for (int i = 0; i < 4; ++i) {
            float ig = sig2(acc[0][i]);
            float fg = sig2(acc[1][i]);
            float gg = tanh2(acc[2][i]);
            float og = sig2(acc[3][i]);
            float c  = fg * c0[i] + ig * gg;
            c0[i] = c;
            h0b[cbo + w0off[i]] = (_Float16)(og * tanh_c(c));
        }
        __syncthreads();

        #pragma unroll
        for (int nt = 0; nt < 4; ++nt) {
            f32x4 b = {bias1[nt], bias1[nt], bias1[nt], bias1[nt]};
            acc[nt] = b;
        }
        #pragma unroll
        for (int kt = 0; kt < 4; ++kt) {
            half8 a0 = *(const half8*)(h0b + cbo + hoff[kt]);
            half8 a1 = *(const half8*)(h1b + pbo + hoff[kt]);
            #pragma unroll
            for (int nt = 0; nt < 4; ++nt)
                acc[nt] = __builtin_amdgcn_mfma_f32_16x16x32_f16(a0, wih1f[nt][kt], acc[nt], 0, 0, 0);
            #pragma unroll
            for (int nt = 0; nt < 4; ++nt) {
                half8 bfr = *(const half8*)(whh1 + nt * 16384 + j0 * 128 + swz[kt]);
                acc[nt] = __builtin_amdgcn_mfma_f32_16x16x32_f16(a1, bfr, acc[nt], 0, 0, 0);
            }
        }
        #pragma unroll
        for (int i = 0; i < 4; ++i) {
            float ig = sig2(acc[0][i]);
            float fg = sig2(acc[1][i]);
            float gg = tanh2(acc[2][i]);
            float og = sig2(acc[3][i]);
            float c  = fg * c1[i] + ig * gg;
            c1[i] = c;
            h1b[cbo + w0off[i]] = (_Float16)(og * tanh_c(c));
        }
        if (w == 7) {
            f32x4 vh = {0.f, 0.f, 0.f, 0.f};
            #pragma unroll
            for (int kt = 0; kt < 4; ++kt) {
                half8 a1 = *(const half8*)(h1b + pbo + hoff[kt]);
                half8 bw = *(const half8*)(woutl + kt * 32 + quad * 8);
                vh = __builtin_amdgcn_mfma_f32_16x16x32_f16(a1, bw, vh, 0, 0, 0);
            }
            if (t > 0 && col == 0) {
                f32x4 vo = {vh[0] + bout, vh[1] + bout, vh[2] + bout, vh[3] + bout};
                *(f32x4*)(out + (size_t)(t - 1) * BATCH + rowbase + quad * 4) = vo;
            }
        }
    }
    __syncthreads();
    if (w == 7) {
        const int fbo = (((T_STEPS - 1) & 1) ^ 1) * 2048;
        f32x4 vh = {0.f, 0.f, 0.f, 0.f};
        #pragma unroll
        for (int kt = 0; kt < 4; ++kt) {
            half8 a1 = *(const half8*)(h1b + fbo + hoff[kt]);
            half8 bw = *(const half8*)(woutl + kt * 32 + quad * 8);
            vh = __builtin_amdgcn_mfma_f32_16x16x32_f16(a1, bw, vh, 0, 0, 0);
        }
        if (col == 0) {
            f32x4 vo = {vh[0] + bout, vh[1] + bout, vh[2] + bout, vh[3] + bout};
            *(f32x4*)(out + (size_t)(T_STEPS - 1) * BATCH + rowbase + quad * 4) = vo;
        }
    }
}

extern "C" void kernel_launch(void* const* d_in, const int* in_sizes, int n_in,
                              void* d_out, int out_size, void* d_ws, size_t ws_size,
                              hipStream_t stream) {
    const float* state = (const float*)d_in[0];
    const float* wih0  = (const float*)d_in[1];
    const float* whh0  = (const float*)d_in[2];
    const float* bih0  = (const float*)d_in[3];
    const float* bhh0  = (const float*)d_in[4];
    const float* wih1  = (const float*)d_in[5];
    const float* whh1  = (const float*)d_in[6];
    const float* bih1  = (const float*)d_in[7];
    const float* bhh1  = (const float*)d_in[8];
    const float* wout  = (const float*)d_in[9];
    const float* bout  = (const float*)d_in[10];
    _Float16* wsh = (_Float16*)d_ws;
    float* outp = (float*)d_out;

    prep_weights<<<896, 256, 0, stream>>>(wih0, whh0, wih1, whh1, wsh);

    if (ws_size >= WS2S_TOTAL) {
        prep_state<<<4096, 256, 0, stream>>>(state, wsh + WH_X2);
        lstm_split<<<64, 256, PIPE_LDS_BYTES, stream>>>(
            wsh, bih0, bhh0, bih1, bhh1, wout, bout,
            wsh + WH_SLAB2, (int*)((char*)d_ws + WB_FLAG2),
            wsh + XBUF_HOFF, wsh + WH_X2, outp);
    } else if (ws_size >= WS2_TOTAL) {
        prep_state<<<4096, 256, 0, stream>>>(state, wsh + WH_X2);
        lstm_pipe<true><<<32, 512, PIPE_LDS_BYTES, stream>>>(
            state, wsh, bih0, bhh0, bih1, bhh1, wout, bout,
            wsh + WH_SLAB2, (int*)((char*)d_ws + WB_FLAG2), wsh + WH_X2, outp);
    } else if (ws_size >= WS1_TOTAL) {
        lstm_pipe<false><<<32, 512, PIPE_LDS_BYTES, stream>>>(
            state, wsh, bih0, bhh0, bih1, bhh1, wout, bout,
            wsh + WH_SLAB1, (int*)((char*)d_ws + WB_FLAG1), nullptr, outp);
    } else if (ws_size >= WS0XH_TOTAL) {
        prep_state<<<4096, 256, 0, stream>>>(state, wsh + WH_X2);
        lstm_mono<true><<<16, 512, MONO_LDS_BYTES, stream>>>(
            state, wsh, bih0, bhh0, bih1, bhh1, wout, bout, outp);
    } else {
        lstm_mono<false><<<16, 512, MONO_LDS_BYTES, stream>>>(
            state, wsh, bih0, bhh0, bih1, bhh1, wout, bout, outp);
    }
}

// Round 9
// 646.904 us; speedup vs baseline: 4.1532x; 4.1532x over previous
//
#include <hip/hip_runtime.h>

// LSTM_Critic: T=512, B=256, D_IN=64, H=128. Round-22 = REVERT to best-known
// (R17/R18-plain lstm_pipe, 523us dispatch) + cheap exact wins:
// (1) mode 1 only: x stays fp32, converted in-register by producers (16 cvt/
//     step, noise). prep_state (1M-thread launch) deleted from the hot path.
// (2) bias-as-MFMA-C: first-kt MFMA takes the pre-splatted bias f32x4 as C
//     directly -- kills the 16-mov acc init per wave per step.
// R21 post-mortem: gate-split via per-step L2 flag exchange = 2639us (~10k
// cyc/step handshake). Cross-CU per-step sync is dead; per-CU matrix time is
// invariant (MFMA M=16 floor x 16 tiles). This structure's measured floor is
// ~2400 cyc/step on 32 CUs; 7 structural probes (operand paths x3, store
// coalesce, overlap x3) moved it < +-5%.

#define T_STEPS 512
#define BATCH   256
#define DIN     64
#define GROUP   16
#define NGRP    (T_STEPS / GROUP)

typedef _Float16 half8 __attribute__((ext_vector_type(8)));
typedef _Float16 half4 __attribute__((ext_vector_type(4)));
typedef float    f32x4 __attribute__((ext_vector_type(4)));

#define LOG2E  1.44269504088896f
#define LOG2E2 2.88539008177793f

// ---- ws layout (fp16 element offsets unless noted) ----
#define WH_IH0 0          // [512][64]
#define WH_HH0 32768      // [512][128]
#define WH_IH1 98304      // [512][128]
#define WH_HH1 163840     // [512][128]
// mode 1: weights + slab + flags (x stays fp32 from input)
#define WH_SLAB1  229376
#define WB_FLAG1  34013184                 // byte offset
#define WS1_TOTAL 34045952

__global__ void prep_weights(const float* __restrict__ wih0,
                             const float* __restrict__ whh0,
                             const float* __restrict__ wih1,
                             const float* __restrict__ whh1,
                             _Float16* __restrict__ ws) {
    int idx = blockIdx.x * 256 + threadIdx.x;   // 229376 total
    float v; int row;
    if (idx < 32768)       { row = idx >> 6;             v = wih0[idx]; }
    else if (idx < 98304)  { row = (idx - 32768) >> 7;   v = whh0[idx - 32768]; }
    else if (idx < 163840) { row = (idx - 98304) >> 7;   v = wih1[idx - 98304]; }
    else                   { row = (idx - 163840) >> 7;  v = whh1[idx - 163840]; }
    // gate chunk 2 (g) uses tanh -> scale 2*log2e; others sigmoid -> log2e
    float sc = ((row >> 7) == 2) ? LOG2E2 : LOG2E;
    ws[idx] = (_Float16)(v * sc);
}

__device__ __forceinline__ float rcpf(float x) { return __builtin_amdgcn_rcpf(x); }
__device__ __forceinline__ float ex2(float x)  { return __builtin_amdgcn_exp2f(x); }

// legacy activations (mono path)
__device__ __forceinline__ float sig2(float y)  { return rcpf(1.0f + ex2(-y)); }
__device__ __forceinline__ float tanh2(float y2){ return 1.0f - 2.0f * rcpf(1.0f + ex2(y2)); }
__device__ __forceinline__ float tanh_c(float c){ return 1.0f - 2.0f * rcpf(1.0f + ex2(c * LOG2E2)); }

// fused activation for one row (5 exp2 + 3 rcp), exact algebra
__device__ __forceinline__ float act_row(float aI, float aF, float aG, float aO,
                                         float& ccv) {
    float Ei = ex2(-aI);
    float Ef = ex2(-aF);
    float Eg = ex2(aG);          // aG pre-scaled by 2*log2e
    float Eo = ex2(-aO);
    float fg  = rcpf(1.0f + Ef);
    float igg = (Eg - 1.0f) * rcpf((1.0f + Ei) * (1.0f + Eg));
    float c   = fg * ccv + igg;
    ccv = c;
    float Ec = ex2(c * LOG2E2);
    return (Ec - 1.0f) * rcpf((1.0f + Eo) * (1.0f + Ec));
}

// LDS (halfs): hdb[2][16][128] = 4096 | woutl[128]
#define PIPE_LDS_BYTES ((4096 + 128) * 2)

// =====================  pipelined kernel (best-known structure)  ============
__global__ __launch_bounds__(512, 1) void lstm_pipe(
        const float* __restrict__ state32, const _Float16* __restrict__ wsw,
        const float* __restrict__ b_ih0, const float* __restrict__ b_hh0,
        const float* __restrict__ b_ih1, const float* __restrict__ b_hh1,
        const float* __restrict__ w_out, const float* __restrict__ b_out,
        _Float16* __restrict__ slab, int* __restrict__ flags,
        float* __restrict__ out) {
    extern __shared__ _Float16 lds[];
    _Float16* hdb   = lds;            // h double-buffer [2][16][128], swizzled
    _Float16* woutl = lds + 4096;     // head weights (consumer)

    const int tid  = threadIdx.x;
    const int w    = tid >> 6;
    const int lane = tid & 63;
    const int col  = lane & 15;
    const int quad = lane >> 4;
    const bool producer = blockIdx.x < 16;
    const int tile = blockIdx.x & 15;
    const int rowbase = tile * 16;
    const int j0 = w * 16 + col;

    // ---- one-time LDS init ----
    {
        half8 z;
        #pragma unroll
        for (int jj = 0; jj < 8; ++jj) z[jj] = (_Float16)0.0f;
        *(half8*)(hdb + tid * 8) = z;   // 512*8 = 4096 halfs
    }
    if (!producer && tid < 128) woutl[tid] = (_Float16)w_out[tid];

    // ---- resident input-side B-frags + pre-splatted scaled biases ----
    half8 wresf[4][4];   // producer uses [nt][0..1] (wih0), consumer [nt][0..3] (wih1)
    f32x4 biasv[4];
    #pragma unroll
    for (int nt = 0; nt < 4; ++nt) {
        int j = nt * 128 + j0;
        float sc = (nt == 2) ? LOG2E2 : LOG2E;
        float b;
        if (producer) {
            #pragma unroll
            for (int kt = 0; kt < 2; ++kt)
                wresf[nt][kt] = *(const half8*)(wsw + WH_IH0 + j * 64 + kt * 32 + quad * 8);
            b = (b_ih0[j] + b_hh0[j]) * sc;
        } else {
            #pragma unroll
            for (int kt = 0; kt < 4; ++kt)
                wresf[nt][kt] = *(const half8*)(wsw + WH_IH1 + j * 128 + kt * 32 + quad * 8);
            b = (b_ih1[j] + b_hh1[j]) * sc;
        }
        f32x4 bv = {b, b, b, b};
        biasv[nt] = bv;
    }
    const float bout = b_out[0];

    // ---- resident RECURRENT B-frags, sourced from GLOBAL ----
    half8 wpf[4][4];
    {
        const _Float16* wrg = wsw + (producer ? WH_HH0 : WH_HH1);
        #pragma unroll
        for (int kt = 0; kt < 4; ++kt)
            #pragma unroll
            for (int nt = 0; nt < 4; ++nt)
                wpf[kt][nt] = *(const half8*)(wrg + (nt * 128 + j0) * 128 + kt * 32 + quad * 8);
    }
    #pragma unroll
    for (int kt = 0; kt < 4; ++kt)
        #pragma unroll
        for (int nt = 0; nt < 4; ++nt)
            asm volatile("" : "+v"(wpf[kt][nt]));

    // swizzled-address precompute (R2-verified, 0 bank conflicts)
    int swz[4], hoff[4], w0off[4];
    #pragma unroll
    for (int kt = 0; kt < 4; ++kt) {
        swz[kt]  = ((kt * 4 + quad) ^ col) * 8;
        hoff[kt] = col * 128 + swz[kt];
    }
    #pragma unroll
    for (int i = 0; i < 4; ++i) {
        int row = quad * 4 + i;
        w0off[i] = row * 128 + (((2 * w + (col >> 3)) ^ row) * 8) + (col & 7);
    }
    float cc[4] = {0.f, 0.f, 0.f, 0.f};

    // coalesced-copy addressing (producer): thread tid handles halfs
    // [tid*4 .. tid*4+4) of the 16x128 h tile. LDS side de-swizzles.
    const int cr   = tid >> 5;            // batch row 0..15
    const int cc0  = (tid & 31) * 4;      // hidden col 0..124
    const int cprd = cr * 128 + (((cc0 >> 3) ^ cr) * 8) + (cc0 & 7);

    __syncthreads();

    if (producer) {
        // ================= layer-0 producer =================
        const float* xpf = state32 + (size_t)(rowbase + col) * DIN + quad * 8;

        // pre-loop: accI(0) = bias + x(0)-part; buffer x(1)
        f32x4 bf0, bf1, bf2, bf3;            // fp32 x buffer for t+1
        f32x4 accI[4];
        {
            f32x4 t0 = *(const f32x4*)(xpf),      t1 = *(const f32x4*)(xpf + 4);
            f32x4 t2 = *(const f32x4*)(xpf + 32), t3 = *(const f32x4*)(xpf + 36);
            half8 a0, a1v;
            #pragma unroll
            for (int jj = 0; jj < 4; ++jj) {
                a0[jj]  = (_Float16)t0[jj]; a0[jj+4]  = (_Float16)t1[jj];
                a1v[jj] = (_Float16)t2[jj]; a1v[jj+4] = (_Float16)t3[jj];
            }
            #pragma unroll
            for (int nt = 0; nt < 4; ++nt)
                accI[nt] = __builtin_amdgcn_mfma_f32_16x16x32_f16(a0, wresf[nt][0], biasv[nt], 0, 0, 0);
            #pragma unroll
            for (int nt = 0; nt < 4; ++nt)
                accI[nt] = __builtin_amdgcn_mfma_f32_16x16x32_f16(a1v, wresf[nt][1], accI[nt], 0, 0, 0);
            bf0 = *(const f32x4*)(xpf + BATCH * DIN);
            bf1 = *(const f32x4*)(xpf + BATCH * DIN + 4);
            bf2 = *(const f32x4*)(xpf + BATCH * DIN + 32);
            bf3 = *(const f32x4*)(xpf + BATCH * DIN + 36);
        }

        #pragma unroll 2
        for (int t = 0; t < T_STEPS; ++t) {
            const int pbo = (t & 1) * 2048, cbo = pbo ^ 2048;
            const int lt = t & (GROUP - 1);
            __syncthreads();   // t-1 LDS writes visible; vmcnt drained

            // coalesced slab copy of h(t-1) from hdb[pbo]: 8B/thread,
            // contiguous 4KB per block-step; drains at the t+1 barrier.
            if (t > 0) {
                half4 hv = *(const half4*)(hdb + pbo + cprd);
                *(half4*)(slab + (size_t)((t - 1) * 16 + tile) * 2048 + tid * 4) = hv;
            }
            // publish group (t/16 - 1) one step later (its last h copy
            // drained at THIS step's barrier)
            if (lt == 1 && t > 16 && tid == 0)
                __hip_atomic_store(flags + ((t >> 4) - 1) * 16 + tile, t >> 4,
                                   __ATOMIC_RELEASE, __HIP_MEMORY_SCOPE_AGENT);

            half8 ah[4];
            #pragma unroll
            for (int kt = 0; kt < 4; ++kt)
                ah[kt] = *(const half8*)(hdb + pbo + hoff[kt]);

            // recurrent MFMAs into accI (which already holds bias + x(t)-part)
            #pragma unroll
            for (int kt = 0; kt < 4; ++kt)
                #pragma unroll
                for (int nt = 0; nt < 4; ++nt)
                    accI[nt] = __builtin_amdgcn_mfma_f32_16x16x32_f16(ah[kt], wpf[kt][nt], accI[nt], 0, 0, 0);

            // prefetch x(t+2) (fp32)
            f32x4 ff0, ff1, ff2, ff3;
            {
                int tn2 = (t + 2 < T_STEPS) ? t + 2 : T_STEPS - 1;
                const float* xq = xpf + (size_t)tn2 * (BATCH * DIN);
                ff0 = *(const f32x4*)(xq);      ff1 = *(const f32x4*)(xq + 4);
                ff2 = *(const f32x4*)(xq + 32); ff3 = *(const f32x4*)(xq + 36);
            }

            // tail: accN(t+1) = bias + x(t+1)-part (bias enters as MFMA C)
            half8 cx0, cx1;
            #pragma unroll
            for (int jj = 0; jj < 4; ++jj) {
                cx0[jj] = (_Float16)bf0[jj]; cx0[jj+4] = (_Float16)bf1[jj];
                cx1[jj] = (_Float16)bf2[jj]; cx1[jj+4] = (_Float16)bf3[jj];
            }
            f32x4 accN[4];
            #pragma unroll
            for (int nt = 0; nt < 4; ++nt)
                accN[nt] = __builtin_amdgcn_mfma_f32_16x16x32_f16(cx0, wresf[nt][0], biasv[nt], 0, 0, 0);
            #pragma unroll
            for (int nt = 0; nt < 4; ++nt)
                accN[nt] = __builtin_amdgcn_mfma_f32_16x16x32_f16(cx1, wresf[nt][1], accN[nt], 0, 0, 0);

            #pragma unroll
            for (int i = 0; i < 4; ++i) {
                float hval = act_row(accI[0][i], accI[1][i], accI[2][i], accI[3][i], cc[i]);
                hdb[cbo + w0off[i]] = (_Float16)hval;   // swizzled
            }

            // rotate pipeline state
            #pragma unroll
            for (int nt = 0; nt < 4; ++nt) accI[nt] = accN[nt];
            bf0 = ff0; bf1 = ff1; bf2 = ff2; bf3 = ff3;
        }
        __syncthreads();   // h(T-1) hdb write visible
        {   // copy h(T-1): written at t=511 into cbo(511) = buffer 0
            half4 hv = *(const half4*)(hdb + 0 + cprd);
            *(half4*)(slab + (size_t)((T_STEPS - 1) * 16 + tile) * 2048 + tid * 4) = hv;
        }
        __syncthreads();   // drain final copy
        if (tid == 0)
            __hip_atomic_store(flags + (NGRP - 1) * 16 + tile, NGRP,
                               __ATOMIC_RELEASE, __HIP_MEMORY_SCOPE_AGENT);
    } else {
        // ================= layer-1 consumer + head =================
        if (tid == 0) {   // wait for group 0
            while (__hip_atomic_load(flags + tile, __ATOMIC_ACQUIRE,
                                     __HIP_MEMORY_SCOPE_AGENT) < 1)
                __builtin_amdgcn_s_sleep(1);
        }
        __syncthreads();   // order acquire before all waves' slab loads

        // pre-loop: accI(0) = bias + h0(0)-part; buffer h0(1)
        half8 uA[4];       // holds h0(t+1) for the tail accN
        f32x4 accI[4];
        {
            const _Float16* s0 = slab + (size_t)tile * 2048;
            half8 cA[4];
            #pragma unroll
            for (int kt = 0; kt < 4; ++kt)
                cA[kt] = *(const half8*)(s0 + col * 128 + kt * 32 + quad * 8);
            #pragma unroll
            for (int nt = 0; nt < 4; ++nt)
                accI[nt] = __builtin_amdgcn_mfma_f32_16x16x32_f16(cA[0], wresf[nt][0], biasv[nt], 0, 0, 0);
            #pragma unroll
            for (int kt = 1; kt < 4; ++kt)
                #pragma unroll
                for (int nt = 0; nt < 4; ++nt)
                    accI[nt] = __builtin_amdgcn_mfma_f32_16x16x32_f16(cA[kt], wresf[nt][kt], accI[nt], 0, 0, 0);
            const _Float16* s1 = slab + (size_t)(16 + tile) * 2048;   // slot 1 (group 0)
            #pragma unroll
            for (int kt = 0; kt < 4; ++kt)
                uA[kt] = *(const half8*)(s1 + col * 128 + kt * 32 + quad * 8);
        }

        #pragma unroll 2
        for (int t = 0; t < T_STEPS; ++t) {
            const int pbo = (t & 1) * 2048, cbo = pbo ^ 2048;
            const int lt = t & (GROUP - 1);
            __syncthreads();   // t-1 LDS writes visible; orders any prior acquire

            half8 a1[4];
            #pragma unroll
            for (int kt = 0; kt < 4; ++kt)
                a1[kt] = *(const half8*)(hdb + pbo + hoff[kt]);

            // recurrent MFMAs into accI (already holds bias + h0(t)-part)
            #pragma unroll
            for (int kt = 0; kt < 4; ++kt)
                #pragma unroll
                for (int nt = 0; nt < 4; ++nt)
                    accI[nt] = __builtin_amdgcn_mfma_f32_16x16x32_f16(a1[kt], wpf[kt][nt], accI[nt], 0, 0, 0);

            // poll NEXT group's flag mid-group; barriers at t+1/t+2 order it
            if (lt == 12 && tid == 0) {
                int g1 = (t >> 4) + 1;
                if (g1 < NGRP) {
                    while (__hip_atomic_load(flags + g1 * 16 + tile, __ATOMIC_ACQUIRE,
                                             __HIP_MEMORY_SCOPE_AGENT) < g1 + 1)
                        __builtin_amdgcn_s_sleep(1);
                }
            }

            // prefetch slab slot t+2 (flag for its group already confirmed)
            half8 fA[4];
            {
                int tn2 = (t + 2 < T_STEPS) ? t + 2 : T_STEPS - 1;
                const _Float16* sq = slab + (size_t)(tn2 * 16 + tile) * 2048;
                #pragma unroll
                for (int kt = 0; kt < 4; ++kt)
                    fA[kt] = *(const half8*)(sq + col * 128 + kt * 32 + quad * 8);
            }

            // tail: accN(t+1) = bias + h0(t+1)-part (bias enters as MFMA C)
            f32x4 accN[4];
            #pragma unroll
            for (int nt = 0; nt < 4; ++nt)
                accN[nt] = __builtin_amdgcn_mfma_f32_16x16x32_f16(uA[0], wresf[nt][0], biasv[nt], 0, 0, 0);
            #pragma unroll
            for (int kt = 1; kt < 4; ++kt)
                #pragma unroll
                for (int nt = 0; nt < 4; ++nt)
                    accN[nt] = __builtin_amdgcn_mfma_f32_16x16x32_f16(uA[kt], wresf[nt][kt], accN[nt], 0, 0, 0);

            #pragma unroll
            for (int i = 0; i < 4; ++i) {
                float hval = act_row(accI[0][i], accI[1][i], accI[2][i], accI[3][i], cc[i]);
                hdb[cbo + w0off[i]] = (_Float16)hval;
            }

            // value head for step t-1 on wave 7 (reads pbo buffer = h1(t-1)).
            // No bw zeroing: output column 0 depends only on col==0 lanes' B.
            if (w == 7) {
                f32x4 vh = {0.f, 0.f, 0.f, 0.f};
                #pragma unroll
                for (int kt = 0; kt < 4; ++kt) {
                    half8 av = *(const half8*)(hdb + pbo + hoff[kt]);
                    half8 bw = *(const half8*)(woutl + kt * 32 + quad * 8);
                    vh = __builtin_amdgcn_mfma_f32_16x16x32_f16(av, bw, vh, 0, 0, 0);
                }
                if (t > 0 && col == 0) {
                    f32x4 vo = {vh[0] + bout, vh[1] + bout, vh[2] + bout, vh[3] + bout};
                    *(f32x4*)(out + (size_t)(t - 1) * BATCH + rowbase + quad * 4) = vo;
                }
            }

            // rotate pipeline state
            #pragma unroll
            for (int nt = 0; nt < 4; ++nt) accI[nt] = accN[nt];
            #pragma unroll
            for (int kt = 0; kt < 4; ++kt) uA[kt] = fA[kt];
        }
        __syncthreads();
        if (w == 7) {   // head for t = T-1
            const int fbo = (((T_STEPS - 1) & 1) ^ 1) * 2048;
            f32x4 vh = {0.f, 0.f, 0.f, 0.f};
            #pragma unroll
            for (int kt = 0; kt < 4; ++kt) {
                half8 av = *(const half8*)(hdb + fbo + hoff[kt]);
                half8 bw = *(const half8*)(woutl + kt * 32 + quad * 8);
                vh = __builtin_amdgcn_mfma_f32_16x16x32_f16(av, bw, vh, 0, 0, 0);
            }
            if (col == 0) {
                f32x4 vo = {vh[0] + bout, vh[1] + bout, vh[2] + bout, vh[3] + bout};
                *(f32x4*)(out + (size_t)(T_STEPS - 1) * BATCH + rowbase + quad * 4) = vo;
            }
        }
    }
}

// =====================  monolithic fallback (tiny ws)  =====
#define MONO_LDS_BYTES ((73728 + 128) * 2)

__global__ __launch_bounds__(512, 2) void lstm_mono(
        const float* __restrict__ state32, const _Float16* __restrict__ wsw,
        const float* __restrict__ b_ih0, const float* __restrict__ b_hh0,
        const float* __restrict__ b_ih1, const float* __restrict__ b_hh1,
        const float* __restrict__ w_out, const float* __restrict__ b_out,
        float* __restrict__ out) {
    extern __shared__ _Float16 lds[];
    _Float16* whh1  = lds;
    _Float16* h0b   = lds + 65536;
    _Float16* h1b   = lds + 69632;
    _Float16* woutl = lds + 73728;

    const int tid  = threadIdx.x;
    const int w    = tid >> 6;
    const int lane = tid & 63;
    const int col  = lane & 15;
    const int quad = lane >> 4;
    const int rowbase = blockIdx.x * 16;
    const int j0 = w * 16 + col;

    const _Float16* whh1g = wsw + WH_HH1;
    #pragma unroll
    for (int it = 0; it < 16; ++it) {
        int flat = (it * 512 + tid) * 8;
        int r = flat >> 7, chunk = (flat >> 3) & 15;
        *(half8*)(whh1 + r * 128 + ((chunk ^ (r & 15)) * 8)) = *(const half8*)(whh1g + flat);
    }
    {
        half8 z;
        #pragma unroll
        for (int jj = 0; jj < 8; ++jj) z[jj] = (_Float16)0.0f;
        for (int i = tid * 8; i < 8192; i += 4096) *(half8*)(h0b + i) = z;
    }
    if (tid < 128) woutl[tid] = (_Float16)w_out[tid];

    half8 whh0f[4][4], wih1f[4][4];
    float bias0[4], bias1[4];
    #pragma unroll
    for (int nt = 0; nt < 4; ++nt) {
        int j = nt * 128 + j0;
        float sc = (nt == 2) ? LOG2E2 : LOG2E;
        #pragma unroll
        for (int kt = 0; kt < 4; ++kt) {
            whh0f[nt][kt] = *(const half8*)(wsw + WH_HH0 + j * 128 + kt * 32 + quad * 8);
            wih1f[nt][kt] = *(const half8*)(wsw + WH_IH1 + j * 128 + kt * 32 + quad * 8);
        }
        bias0[nt] = (b_ih0[j] + b_hh0[j]) * sc;
        bias1[nt] = (b_ih1[j] + b_hh1[j]) * sc;
    }
    const float bout = b_out[0];

    int swz[4], hoff[4], w0off[4];
    #pragma unroll
    for (int kt = 0; kt < 4; ++kt) {
        swz[kt]  = ((kt * 4 + quad) ^ col) * 8;
        hoff[kt] = col * 128 + swz[kt];
    }
    #pragma unroll
    for (int i = 0; i < 4; ++i) {
        int row = quad * 4 + i;
        w0off[i] = row * 128 + (((2 * w + (col >> 3)) ^ row) * 8) + (col & 7);
    }
    float c0[4] = {0.f,0.f,0.f,0.f}, c1[4] = {0.f,0.f,0.f,0.f};

    const float* xpf = state32 + (size_t)(rowbase + col) * DIN + quad * 8;
    f32x4 nxf0 = *(const f32x4*)(xpf),      nxf1 = *(const f32x4*)(xpf + 4);
    f32x4 nxf2 = *(const f32x4*)(xpf + 32), nxf3 = *(const f32x4*)(xpf + 36);
    __syncthreads();
    const _Float16* wih0g = wsw + WH_IH0;

    #pragma unroll 1
    for (int t = 0; t < T_STEPS; ++t) {
        const int pbo = (t & 1) * 2048, cbo = pbo ^ 2048;
        half8 ax0, ax1;
        #pragma unroll
        for (int jj = 0; jj < 4; ++jj) {
            ax0[jj]   = (_Float16)nxf0[jj]; ax0[jj+4] = (_Float16)nxf1[jj];
            ax1[jj]   = (_Float16)nxf2[jj]; ax1[jj+4] = (_Float16)nxf3[jj];
        }
        half8 wif[4][2];
        #pragma unroll
        for (int nt = 0; nt < 4; ++nt)
            #pragma unroll
            for (int kt = 0; kt < 2; ++kt)
                wif[nt][kt] = *(const half8*)(wih0g + (nt * 128 + j0) * 64 + kt * 32 + quad * 8);
        half8 ah[4];
        #pragma unroll
        for (int kt = 0; kt < 4; ++kt)
            ah[kt] = *(const half8*)(h0b + pbo + hoff[kt]);

        f32x4 acc[4];
        #pragma unroll
        for (int nt = 0; nt < 4; ++nt) {
            f32x4 b = {bias0[nt], bias0[nt], bias0[nt], bias0[nt]};
            acc[nt] = b;
        }
        #pragma unroll
        for (int kt = 0; kt < 4; ++kt)
            #pragma unroll
            for (int nt = 0; nt < 4; ++nt)
                acc[nt] = __builtin_amdgcn_mfma_f32_16x16x32_f16(ah[kt], whh0f[nt][kt], acc[nt], 0, 0, 0);
        #pragma unroll
        for (int kt = 0; kt < 2; ++kt) {
            half8 axk = kt ? ax1 : ax0;
            #pragma unroll
            for (int nt = 0; nt < 4; ++nt)
                acc[nt] = __builtin_amdgcn_mfma_f32_16x16x32_f16(axk, wif[nt][kt], acc[nt], 0, 0, 0);
        }
        {
            int tn = (t + 1 < T_STEPS) ? t + 1 : t;
            const float* xq = xpf + (size_t)tn * (BATCH * DIN);
            nxf0 = *(const f32x4*)(xq);      nxf1 = *(const f32x4*)(xq + 4);
            nxf2 = *(const f32x4*)(xq + 32); nxf3 = *(const f32x4*)(xq + 36);
        }
        #pragma unroll
        for (int i = 0; i < 4; ++i) {
            float ig = sig2(acc[0][i]);
            float fg = sig2(acc[1][i]);
            float gg = tanh2(acc[2][i]);
            float og = sig2(acc[3][i]);
            float c  = fg * c0[i] + ig * gg;
            c0[i] = c;
            h0b[cbo + w0off[i]] = (_Float16)(og * tanh_c(c));
        }
        __syncthreads();

        #pragma unroll
        for (int nt = 0; nt < 4; ++nt) {
            f32x4 b = {bias1[nt], bias1[nt], bias1[nt], bias1[nt]};
            acc[nt] = b;
        }
        #pragma unroll
        for (int kt = 0; kt < 4; ++kt) {
            half8 a0 = *(const half8*)(h0b + cbo + hoff[kt]);
            half8 a1 = *(const half8*)(h1b + pbo + hoff[kt]);
            #pragma unroll
            for (int nt = 0; nt < 4; ++nt)
                acc[nt] = __builtin_amdgcn_mfma_f32_16x16x32_f16(a0, wih1f[nt][kt], acc[nt], 0, 0, 0);
            #pragma unroll
            for (int nt = 0; nt < 4; ++nt) {
                half8 bfr = *(const half8*)(whh1 + nt * 16384 + j0 * 128 + swz[kt]);
                acc[nt] = __builtin_amdgcn_mfma_f32_16x16x32_f16(a1, bfr, acc[nt], 0, 0, 0);
            }
        }
        #pragma unroll
        for (int i = 0; i < 4; ++i) {
            float ig = sig2(acc[0][i]);
            float fg = sig2(acc[1][i]);
            float gg = tanh2(acc[2][i]);
            float og = sig2(acc[3][i]);
            float c  = fg * c1[i] + ig * gg;
            c1[i] = c;
            h1b[cbo + w0off[i]] = (_Float16)(og * tanh_c(c));
        }
        if (w == 7) {
            f32x4 vh = {0.f, 0.f, 0.f, 0.f};
            #pragma unroll
            for (int kt = 0; kt < 4; ++kt) {
                half8 a1 = *(const half8*)(h1b + pbo + hoff[kt]);
                half8 bw = *(const half8*)(woutl + kt * 32 + quad * 8);
                vh = __builtin_amdgcn_mfma_f32_16x16x32_f16(a1, bw, vh, 0, 0, 0);
            }
            if (t > 0 && col == 0) {
                f32x4 vo = {vh[0] + bout, vh[1] + bout, vh[2] + bout, vh[3] + bout};
                *(f32x4*)(out + (size_t)(t - 1) * BATCH + rowbase + quad * 4) = vo;
            }
        }
    }
    __syncthreads();
    if (w == 7) {
        const int fbo = (((T_STEPS - 1) & 1) ^ 1) * 2048;
        f32x4 vh = {0.f, 0.f, 0.f, 0.f};
        #pragma unroll
        for (int kt = 0; kt < 4; ++kt) {
            half8 a1 = *(const half8*)(h1b + fbo + hoff[kt]);
            half8 bw = *(const half8*)(woutl + kt * 32 + quad * 8);
            vh = __builtin_amdgcn_mfma_f32_16x16x32_f16(a1, bw, vh, 0, 0, 0);
        }
        if (col == 0) {
            f32x4 vo = {vh[0] + bout, vh[1] + bout, vh[2] + bout, vh[3] + bout};
            *(f32x4*)(out + (size_t)(T_STEPS - 1) * BATCH + rowbase + quad * 4) = vo;
        }
    }
}

extern "C" void kernel_launch(void* const* d_in, const int* in_sizes, int n_in,
                              void* d_out, int out_size, void* d_ws, size_t ws_size,
                              hipStream_t stream) {
    const float* state = (const float*)d_in[0];
    const float* wih0  = (const float*)d_in[1];
    const float* whh0  = (const float*)d_in[2];
    const float* bih0  = (const float*)d_in[3];
    const float* bhh0  = (const float*)d_in[4];
    const float* wih1  = (const float*)d_in[5];
    const float* whh1  = (const float*)d_in[6];
    const float* bih1  = (const float*)d_in[7];
    const float* bhh1  = (const float*)d_in[8];
    const float* wout  = (const float*)d_in[9];
    const float* bout  = (const float*)d_in[10];
    _Float16* wsh = (_Float16*)d_ws;
    float* outp = (float*)d_out;

    prep_weights<<<896, 256, 0, stream>>>(wih0, whh0, wih1, whh1, wsh);

    if (ws_size >= WS1_TOTAL) {
        lstm_pipe<<<32, 512, PIPE_LDS_BYTES, stream>>>(
            state, wsh, bih0, bhh0, bih1, bhh1, wout, bout,
            wsh + WH_SLAB1, (int*)((char*)d_ws + WB_FLAG1), outp);
    } else {
        lstm_mono<<<16, 512, MONO_LDS_BYTES, stream>>>(
            state, wsh, bih0, bhh0, bih1, bhh1, wout, bout, outp);
    }
}

// Round 10
// 596.219 us; speedup vs baseline: 4.5062x; 1.0850x over previous
//
#include <hip/hip_runtime.h>

// LSTM_Critic: T=512, B=256, D_IN=64, H=128. Round-23 = RESTORE mode 2
// (fp16 x via prep_state, XH=true) which R22 wrongly dropped: fp32-x loads
// added +8.3GB FETCH/dispatch and +60-100us (580-628 vs 521-523). Keep R22's
// bias-as-MFMA-C (strictly fewer instructions, not implicated in the
// regression). This is the best-known R17/R18-plain structure.
// Ledger: operand sourcing x3, store coalesce, epilogue fusion, overlap x3,
// CU-split x1, x-precision x1 all measured; step pinned ~2400 cyc serialized
// per-SIMD issue + barrier on 32 CUs; cross-CU handshake 5x worse.

#define T_STEPS 512
#define BATCH   256
#define DIN     64
#define GROUP   16
#define NGRP    (T_STEPS / GROUP)

typedef _Float16 half8 __attribute__((ext_vector_type(8)));
typedef _Float16 half4 __attribute__((ext_vector_type(4)));
typedef float    f32x4 __attribute__((ext_vector_type(4)));

#define LOG2E  1.44269504088896f
#define LOG2E2 2.88539008177793f

// ---- ws layout (fp16 element offsets unless noted) ----
#define WH_IH0 0          // [512][64]
#define WH_HH0 32768      // [512][128]
#define WH_IH1 98304      // [512][128]
#define WH_HH1 163840     // [512][128]
// mode 2: + fp16 x + slab + flags
#define WH_X2     229376                   // 8388608 halfs
#define WH_SLAB2  8617984                  // 16777216 halfs (512*16*2048)
#define WB_FLAG2  50790400                 // byte offset, 8192 ints reserved
#define WS2_TOTAL 50823168
// mode 1: + slab + flags (x stays fp32 from input)
#define WH_SLAB1  229376
#define WB_FLAG1  34013184
#define WS1_TOTAL 34045952

__global__ void prep_weights(const float* __restrict__ wih0,
                             const float* __restrict__ whh0,
                             const float* __restrict__ wih1,
                             const float* __restrict__ whh1,
                             _Float16* __restrict__ ws) {
    int idx = blockIdx.x * 256 + threadIdx.x;   // 229376 total
    float v; int row;
    if (idx < 32768)       { row = idx >> 6;             v = wih0[idx]; }
    else if (idx < 98304)  { row = (idx - 32768) >> 7;   v = whh0[idx - 32768]; }
    else if (idx < 163840) { row = (idx - 98304) >> 7;   v = wih1[idx - 98304]; }
    else                   { row = (idx - 163840) >> 7;  v = whh1[idx - 163840]; }
    // gate chunk 2 (g) uses tanh -> scale 2*log2e; others sigmoid -> log2e
    float sc = ((row >> 7) == 2) ? LOG2E2 : LOG2E;
    ws[idx] = (_Float16)(v * sc);
}

__global__ void prep_state(const float* __restrict__ s, _Float16* __restrict__ d) {
    int i = (blockIdx.x * 256 + threadIdx.x) * 8;   // 8388608 elements
    f32x4 a = *(const f32x4*)(s + i);
    f32x4 b = *(const f32x4*)(s + i + 4);
    half8 h;
    h[0]=(_Float16)a[0]; h[1]=(_Float16)a[1]; h[2]=(_Float16)a[2]; h[3]=(_Float16)a[3];
    h[4]=(_Float16)b[0]; h[5]=(_Float16)b[1]; h[6]=(_Float16)b[2]; h[7]=(_Float16)b[3];
    *(half8*)(d + i) = h;
}

__device__ __forceinline__ float rcpf(float x) { return __builtin_amdgcn_rcpf(x); }
__device__ __forceinline__ float ex2(float x)  { return __builtin_amdgcn_exp2f(x); }

// legacy activations (mono path)
__device__ __forceinline__ float sig2(float y)  { return rcpf(1.0f + ex2(-y)); }
__device__ __forceinline__ float tanh2(float y2){ return 1.0f - 2.0f * rcpf(1.0f + ex2(y2)); }
__device__ __forceinline__ float tanh_c(float c){ return 1.0f - 2.0f * rcpf(1.0f + ex2(c * LOG2E2)); }

// fused activation for one row (5 exp2 + 3 rcp), exact algebra
__device__ __forceinline__ float act_row(float aI, float aF, float aG, float aO,
                                         float& ccv) {
    float Ei = ex2(-aI);
    float Ef = ex2(-aF);
    float Eg = ex2(aG);          // aG pre-scaled by 2*log2e
    float Eo = ex2(-aO);
    float fg  = rcpf(1.0f + Ef);
    float igg = (Eg - 1.0f) * rcpf((1.0f + Ei) * (1.0f + Eg));
    float c   = fg * ccv + igg;
    ccv = c;
    float Ec = ex2(c * LOG2E2);
    return (Ec - 1.0f) * rcpf((1.0f + Eo) * (1.0f + Ec));
}

// LDS (halfs): hdb[2][16][128] = 4096 | woutl[128]
#define PIPE_LDS_BYTES ((4096 + 128) * 2)

// =====================  pipelined kernel (best-known structure)  ============
template<bool XH>
__global__ __launch_bounds__(512, 1) void lstm_pipe(
        const float* __restrict__ state32, const _Float16* __restrict__ wsw,
        const float* __restrict__ b_ih0, const float* __restrict__ b_hh0,
        const float* __restrict__ b_ih1, const float* __restrict__ b_hh1,
        const float* __restrict__ w_out, const float* __restrict__ b_out,
        _Float16* __restrict__ slab, int* __restrict__ flags,
        const _Float16* __restrict__ xh, float* __restrict__ out) {
    extern __shared__ _Float16 lds[];
    _Float16* hdb   = lds;            // h double-buffer [2][16][128], swizzled
    _Float16* woutl = lds + 4096;     // head weights (consumer)

    const int tid  = threadIdx.x;
    const int w    = tid >> 6;
    const int lane = tid & 63;
    const int col  = lane & 15;
    const int quad = lane >> 4;
    const bool producer = blockIdx.x < 16;
    const int tile = blockIdx.x & 15;
    const int rowbase = tile * 16;
    const int j0 = w * 16 + col;

    // ---- one-time LDS init ----
    {
        half8 z;
        #pragma unroll
        for (int jj = 0; jj < 8; ++jj) z[jj] = (_Float16)0.0f;
        *(half8*)(hdb + tid * 8) = z;   // 512*8 = 4096 halfs
    }
    if (!producer && tid < 128) woutl[tid] = (_Float16)w_out[tid];

    // ---- resident input-side B-frags + pre-splatted scaled biases ----
    half8 wresf[4][4];   // producer uses [nt][0..1] (wih0), consumer [nt][0..3] (wih1)
    f32x4 biasv[4];
    #pragma unroll
    for (int nt = 0; nt < 4; ++nt) {
        int j = nt * 128 + j0;
        float sc = (nt == 2) ? LOG2E2 : LOG2E;
        float b;
        if (producer) {
            #pragma unroll
            for (int kt = 0; kt < 2; ++kt)
                wresf[nt][kt] = *(const half8*)(wsw + WH_IH0 + j * 64 + kt * 32 + quad * 8);
            b = (b_ih0[j] + b_hh0[j]) * sc;
        } else {
            #pragma unroll
            for (int kt = 0; kt < 4; ++kt)
                wresf[nt][kt] = *(const half8*)(wsw + WH_IH1 + j * 128 + kt * 32 + quad * 8);
            b = (b_ih1[j] + b_hh1[j]) * sc;
        }
        f32x4 bv = {b, b, b, b};
        biasv[nt] = bv;
    }
    const float bout = b_out[0];

    // ---- resident RECURRENT B-frags, sourced from GLOBAL ----
    half8 wpf[4][4];
    {
        const _Float16* wrg = wsw + (producer ? WH_HH0 : WH_HH1);
        #pragma unroll
        for (int kt = 0; kt < 4; ++kt)
            #pragma unroll
            for (int nt = 0; nt < 4; ++nt)
                wpf[kt][nt] = *(const half8*)(wrg + (nt * 128 + j0) * 128 + kt * 32 + quad * 8);
    }
    #pragma unroll
    for (int kt = 0; kt < 4; ++kt)
        #pragma unroll
        for (int nt = 0; nt < 4; ++nt)
            asm volatile("" : "+v"(wpf[kt][nt]));

    // swizzled-address precompute (R2-verified, 0 bank conflicts)
    int swz[4], hoff[4], w0off[4];
    #pragma unroll
    for (int kt = 0; kt < 4; ++kt) {
        swz[kt]  = ((kt * 4 + quad) ^ col) * 8;
        hoff[kt] = col * 128 + swz[kt];
    }
    #pragma unroll
    for (int i = 0; i < 4; ++i) {
        int row = quad * 4 + i;
        w0off[i] = row * 128 + (((2 * w + (col >> 3)) ^ row) * 8) + (col & 7);
    }
    float cc[4] = {0.f, 0.f, 0.f, 0.f};

    // coalesced-copy addressing (producer): thread tid handles halfs
    // [tid*4 .. tid*4+4) of the 16x128 h tile. LDS side de-swizzles.
    const int cr   = tid >> 5;            // batch row 0..15
    const int cc0  = (tid & 31) * 4;      // hidden col 0..124
    const int cprd = cr * 128 + (((cc0 >> 3) ^ cr) * 8) + (cc0 & 7);

    __syncthreads();

    if (producer) {
        // ================= layer-0 producer =================
        const _Float16* xph = xh + (size_t)(rowbase + col) * DIN + quad * 8;
        const float*    xpf = state32 + (size_t)(rowbase + col) * DIN + quad * 8;

        // pre-loop: accI(0) = bias + x(0)-part; buffer x(1)
        half8 bx0, bx1;                      // XH buffer holding x(t+1)
        f32x4 bf0, bf1, bf2, bf3;            // non-XH buffer
        f32x4 accI[4];
        {
            half8 a0, a1v;
            if constexpr (XH) {
                a0  = *(const half8*)(xph);
                a1v = *(const half8*)(xph + 32);
            } else {
                f32x4 t0 = *(const f32x4*)(xpf),      t1 = *(const f32x4*)(xpf + 4);
                f32x4 t2 = *(const f32x4*)(xpf + 32), t3 = *(const f32x4*)(xpf + 36);
                #pragma unroll
                for (int jj = 0; jj < 4; ++jj) {
                    a0[jj]  = (_Float16)t0[jj]; a0[jj+4]  = (_Float16)t1[jj];
                    a1v[jj] = (_Float16)t2[jj]; a1v[jj+4] = (_Float16)t3[jj];
                }
            }
            #pragma unroll
            for (int nt = 0; nt < 4; ++nt)
                accI[nt] = __builtin_amdgcn_mfma_f32_16x16x32_f16(a0, wresf[nt][0], biasv[nt], 0, 0, 0);
            #pragma unroll
            for (int nt = 0; nt < 4; ++nt)
                accI[nt] = __builtin_amdgcn_mfma_f32_16x16x32_f16(a1v, wresf[nt][1], accI[nt], 0, 0, 0);
            // buffer x(1)
            if constexpr (XH) {
                bx0 = *(const half8*)(xph + BATCH * DIN);
                bx1 = *(const half8*)(xph + BATCH * DIN + 32);
            } else {
                bf0 = *(const f32x4*)(xpf + BATCH * DIN);
                bf1 = *(const f32x4*)(xpf + BATCH * DIN + 4);
                bf2 = *(const f32x4*)(xpf + BATCH * DIN + 32);
                bf3 = *(const f32x4*)(xpf + BATCH * DIN + 36);
            }
        }

        #pragma unroll 2
        for (int t = 0; t < T_STEPS; ++t) {
            const int pbo = (t & 1) * 2048, cbo = pbo ^ 2048;
            const int lt = t & (GROUP - 1);
            __syncthreads();   // t-1 LDS writes visible; vmcnt drained

            // coalesced slab copy of h(t-1) from hdb[pbo]: 8B/thread,
            // contiguous 4KB per block-step; drains at the t+1 barrier.
            if (t > 0) {
                half4 hv = *(const half4*)(hdb + pbo + cprd);
                *(half4*)(slab + (size_t)((t - 1) * 16 + tile) * 2048 + tid * 4) = hv;
            }
            // publish group (t/16 - 1) one step later (its last h copy
            // drained at THIS step's barrier)
            if (lt == 1 && t > 16 && tid == 0)
                __hip_atomic_store(flags + ((t >> 4) - 1) * 16 + tile, t >> 4,
                                   __ATOMIC_RELEASE, __HIP_MEMORY_SCOPE_AGENT);

            half8 ah[4];
            #pragma unroll
            for (int kt = 0; kt < 4; ++kt)
                ah[kt] = *(const half8*)(hdb + pbo + hoff[kt]);

            // recurrent MFMAs into accI (which already holds bias + x(t)-part)
            #pragma unroll
            for (int kt = 0; kt < 4; ++kt)
                #pragma unroll
                for (int nt = 0; nt < 4; ++nt)
                    accI[nt] = __builtin_amdgcn_mfma_f32_16x16x32_f16(ah[kt], wpf[kt][nt], accI[nt], 0, 0, 0);

            // prefetch x(t+2)
            half8 fx0, fx1;
            f32x4 ff0, ff1, ff2, ff3;
            {
                int tn2 = (t + 2 < T_STEPS) ? t + 2 : T_STEPS - 1;
                if constexpr (XH) {
                    const _Float16* xq = xph + (size_t)tn2 * (BATCH * DIN);
                    fx0 = *(const half8*)(xq);
                    fx1 = *(const half8*)(xq + 32);
                } else {
                    const float* xq = xpf + (size_t)tn2 * (BATCH * DIN);
                    ff0 = *(const f32x4*)(xq);      ff1 = *(const f32x4*)(xq + 4);
                    ff2 = *(const f32x4*)(xq + 32); ff3 = *(const f32x4*)(xq + 36);
                }
            }

            // tail: accN(t+1) = bias + x(t+1)-part (bias enters as MFMA C)
            half8 cx0, cx1;
            if constexpr (XH) { cx0 = bx0; cx1 = bx1; }
            else {
                #pragma unroll
                for (int jj = 0; jj < 4; ++jj) {
                    cx0[jj] = (_Float16)bf0[jj]; cx0[jj+4] = (_Float16)bf1[jj];
                    cx1[jj] = (_Float16)bf2[jj]; cx1[jj+4] = (_Float16)bf3[jj];
                }
            }
            f32x4 accN[4];
            #pragma unroll
            for (int nt = 0; nt < 4; ++nt)
                accN[nt] = __builtin_amdgcn_mfma_f32_16x16x32_f16(cx0, wresf[nt][0], biasv[nt], 0, 0, 0);
            #pragma unroll
            for (int nt = 0; nt < 4; ++nt)
                accN[nt] = __builtin_amdgcn_mfma_f32_16x16x32_f16(cx1, wresf[nt][1], accN[nt], 0, 0, 0);

            #pragma unroll
            for (int i = 0; i < 4; ++i) {
                float hval = act_row(accI[0][i], accI[1][i], accI[2][i], accI[3][i], cc[i]);
                hdb[cbo + w0off[i]] = (_Float16)hval;   // swizzled
            }

            // rotate pipeline state
            #pragma unroll
            for (int nt = 0; nt < 4; ++nt) accI[nt] = accN[nt];
            if constexpr (XH) { bx0 = fx0; bx1 = fx1; }
            else { bf0 = ff0; bf1 = ff1; bf2 = ff2; bf3 = ff3; }
        }
        __syncthreads();   // h(T-1) hdb write visible
        {   // copy h(T-1): written at t=511 into cbo(511) = buffer 0
            half4 hv = *(const half4*)(hdb + 0 + cprd);
            *(half4*)(slab + (size_t)((T_STEPS - 1) * 16 + tile) * 2048 + tid * 4) = hv;
        }
        __syncthreads();   // drain final copy
        if (tid == 0)
            __hip_atomic_store(flags + (NGRP - 1) * 16 + tile, NGRP,
                               __ATOMIC_RELEASE, __HIP_MEMORY_SCOPE_AGENT);
    } else {
        // ================= layer-1 consumer + head =================
        if (tid == 0) {   // wait for group 0
            while (__hip_atomic_load(flags + tile, __ATOMIC_ACQUIRE,
                                     __HIP_MEMORY_SCOPE_AGENT) < 1)
                __builtin_amdgcn_s_sleep(1);
        }
        __syncthreads();   // order acquire before all waves' slab loads

        // pre-loop: accI(0) = bias + h0(0)-part; buffer h0(1)
        half8 uA[4];       // holds h0(t+1) for the tail accN
        f32x4 accI[4];
        {
            const _Float16* s0 = slab + (size_t)tile * 2048;
            half8 cA[4];
            #pragma unroll
            for (int kt = 0; kt < 4; ++kt)
                cA[kt] = *(const half8*)(s0 + col * 128 + kt * 32 + quad * 8);
            #pragma unroll
            for (int nt = 0; nt < 4; ++nt)
                accI[nt] = __builtin_amdgcn_mfma_f32_16x16x32_f16(cA[0], wresf[nt][0], biasv[nt], 0, 0, 0);
            #pragma unroll
            for (int kt = 1; kt < 4; ++kt)
                #pragma unroll
                for (int nt = 0; nt < 4; ++nt)
                    accI[nt] = __builtin_amdgcn_mfma_f32_16x16x32_f16(cA[kt], wresf[nt][kt], accI[nt], 0, 0, 0);
            const _Float16* s1 = slab + (size_t)(16 + tile) * 2048;   // slot 1 (group 0)
            #pragma unroll
            for (int kt = 0; kt < 4; ++kt)
                uA[kt] = *(const half8*)(s1 + col * 128 + kt * 32 + quad * 8);
        }

        #pragma unroll 2
        for (int t = 0; t < T_STEPS; ++t) {
            const int pbo = (t & 1) * 2048, cbo = pbo ^ 2048;
            const int lt = t & (GROUP - 1);
            __syncthreads();   // t-1 LDS writes visible; orders any prior acquire

            half8 a1[4];
            #pragma unroll
            for (int kt = 0; kt < 4; ++kt)
                a1[kt] = *(const half8*)(hdb + pbo + hoff[kt]);

            // recurrent MFMAs into accI (already holds bias + h0(t)-part)
            #pragma unroll
            for (int kt = 0; kt < 4; ++kt)
                #pragma unroll
                for (int nt = 0; nt < 4; ++nt)
                    accI[nt] = __builtin_amdgcn_mfma_f32_16x16x32_f16(a1[kt], wpf[kt][nt], accI[nt], 0, 0, 0);

            // poll NEXT group's flag mid-group; barriers at t+1/t+2 order it
            if (lt == 12 && tid == 0) {
                int g1 = (t >> 4) + 1;
                if (g1 < NGRP) {
                    while (__hip_atomic_load(flags + g1 * 16 + tile, __ATOMIC_ACQUIRE,
                                             __HIP_MEMORY_SCOPE_AGENT) < g1 + 1)
                        __builtin_amdgcn_s_sleep(1);
                }
            }

            // prefetch slab slot t+2 (flag for its group already confirmed)
            half8 fA[4];
            {
                int tn2 = (t + 2 < T_STEPS) ? t + 2 : T_STEPS - 1;
                const _Float16* sq = slab + (size_t)(tn2 * 16 + tile) * 2048;
                #pragma unroll
                for (int kt = 0; kt < 4; ++kt)
                    fA[kt] = *(const half8*)(sq + col * 128 + kt * 32 + quad * 8);
            }

            // tail: accN(t+1) = bias + h0(t+1)-part (bias enters as MFMA C)
            f32x4 accN[4];
            #pragma unroll
            for (int nt = 0; nt < 4; ++nt)
                accN[nt] = __builtin_amdgcn_mfma_f32_16x16x32_f16(uA[0], wresf[nt][0], biasv[nt], 0, 0, 0);
            #pragma unroll
            for (int kt = 1; kt < 4; ++kt)
                #pragma unroll
                for (int nt = 0; nt < 4; ++nt)
                    accN[nt] = __builtin_amdgcn_mfma_f32_16x16x32_f16(uA[kt], wresf[nt][kt], accN[nt], 0, 0, 0);

            #pragma unroll
            for (int i = 0; i < 4; ++i) {
                float hval = act_row(accI[0][i], accI[1][i], accI[2][i], accI[3][i], cc[i]);
                hdb[cbo + w0off[i]] = (_Float16)hval;
            }

            // value head for step t-1 on wave 7 (reads pbo buffer = h1(t-1)).
            // No bw zeroing: output column 0 depends only on col==0 lanes' B.
            if (w == 7) {
                f32x4 vh = {0.f, 0.f, 0.f, 0.f};
                #pragma unroll
                for (int kt = 0; kt < 4; ++kt) {
                    half8 av = *(const half8*)(hdb + pbo + hoff[kt]);
                    half8 bw = *(const half8*)(woutl + kt * 32 + quad * 8);
                    vh = __builtin_amdgcn_mfma_f32_16x16x32_f16(av, bw, vh, 0, 0, 0);
                }
                if (t > 0 && col == 0) {
                    f32x4 vo = {vh[0] + bout, vh[1] + bout, vh[2] + bout, vh[3] + bout};
                    *(f32x4*)(out + (size_t)(t - 1) * BATCH + rowbase + quad * 4) = vo;
                }
            }

            // rotate pipeline state
            #pragma unroll
            for (int nt = 0; nt < 4; ++nt) accI[nt] = accN[nt];
            #pragma unroll
            for (int kt = 0; kt < 4; ++kt) uA[kt] = fA[kt];
        }
        __syncthreads();
        if (w == 7) {   // head for t = T-1
            const int fbo = (((T_STEPS - 1) & 1) ^ 1) * 2048;
            f32x4 vh = {0.f, 0.f, 0.f, 0.f};
            #pragma unroll
            for (int kt = 0; kt < 4; ++kt) {
                half8 av = *(const half8*)(hdb + fbo + hoff[kt]);
                half8 bw = *(const half8*)(woutl + kt * 32 + quad * 8);
                vh = __builtin_amdgcn_mfma_f32_16x16x32_f16(av, bw, vh, 0, 0, 0);
            }
            if (col == 0) {
                f32x4 vo = {vh[0] + bout, vh[1] + bout, vh[2] + bout, vh[3] + bout};
                *(f32x4*)(out + (size_t)(T_STEPS - 1) * BATCH + rowbase + quad * 4) = vo;
            }
        }
    }
}

// =====================  monolithic fallback (tiny ws)  =====
#define MONO_LDS_BYTES ((73728 + 128) * 2)

__global__ __launch_bounds__(512, 2) void lstm_mono(
        const float* __restrict__ state32, const _Float16* __restrict__ wsw,
        const float* __restrict__ b_ih0, const float* __restrict__ b_hh0,
        const float* __restrict__ b_ih1, const float* __restrict__ b_hh1,
        const float* __restrict__ w_out, const float* __restrict__ b_out,
        float* __restrict__ out) {
    extern __shared__ _Float16 lds[];
    _Float16* whh1  = lds;
    _Float16* h0b   = lds + 65536;
    _Float16* h1b   = lds + 69632;
    _Float16* woutl = lds + 73728;

    const int tid  = threadIdx.x;
    const int w    = tid >> 6;
    const int lane = tid & 63;
    const int col  = lane & 15;
    const int quad = lane >> 4;
    const int rowbase = blockIdx.x * 16;
    const int j0 = w * 16 + col;

    const _Float16* whh1g = wsw + WH_HH1;
    #pragma unroll
    for (int it = 0; it < 16; ++it) {
        int flat = (it * 512 + tid) * 8;
        int r = flat >> 7, chunk = (flat >> 3) & 15;
        *(half8*)(whh1 + r * 128 + ((chunk ^ (r & 15)) * 8)) = *(const half8*)(whh1g + flat);
    }
    {
        half8 z;
        #pragma unroll
        for (int jj = 0; jj < 8; ++jj) z[jj] = (_Float16)0.0f;
        for (int i = tid * 8; i < 8192; i += 4096) *(half8*)(h0b + i) = z;
    }
    if (tid < 128) woutl[tid] = (_Float16)w_out[tid];

    half8 whh0f[4][4], wih1f[4][4];
    float bias0[4], bias1[4];
    #pragma unroll
    for (int nt = 0; nt < 4; ++nt) {
        int j = nt * 128 + j0;
        float sc = (nt == 2) ? LOG2E2 : LOG2E;
        #pragma unroll
        for (int kt = 0; kt < 4; ++kt) {
            whh0f[nt][kt] = *(const half8*)(wsw + WH_HH0 + j * 128 + kt * 32 + quad * 8);
            wih1f[nt][kt] = *(const half8*)(wsw + WH_IH1 + j * 128 + kt * 32 + quad * 8);
        }
        bias0[nt] = (b_ih0[j] + b_hh0[j]) * sc;
        bias1[nt] = (b_ih1[j] + b_hh1[j]) * sc;
    }
    const float bout = b_out[0];

    int swz[4], hoff[4], w0off[4];
    #pragma unroll
    for (int kt = 0; kt < 4; ++kt) {
        swz[kt]  = ((kt * 4 + quad) ^ col) * 8;
        hoff[kt] = col * 128 + swz[kt];
    }
    #pragma unroll
    for (int i = 0; i < 4; ++i) {
        int row = quad * 4 + i;
        w0off[i] = row * 128 + (((2 * w + (col >> 3)) ^ row) * 8) + (col & 7);
    }
    float c0[4] = {0.f,0.f,0.f,0.f}, c1[4] = {0.f,0.f,0.f,0.f};

    const float* xpf = state32 + (size_t)(rowbase + col) * DIN + quad * 8;
    f32x4 nxf0 = *(const f32x4*)(xpf),      nxf1 = *(const f32x4*)(xpf + 4);
    f32x4 nxf2 = *(const f32x4*)(xpf + 32), nxf3 = *(const f32x4*)(xpf + 36);
    __syncthreads();
    const _Float16* wih0g = wsw + WH_IH0;

    #pragma unroll 1
    for (int t = 0; t < T_STEPS; ++t) {
        const int pbo = (t & 1) * 2048, cbo = pbo ^ 2048;
        half8 ax0, ax1;
        #pragma unroll
        for (int jj = 0; jj < 4; ++jj) {
            ax0[jj]   = (_Float16)nxf0[jj]; ax0[jj+4] = (_Float16)nxf1[jj];
            ax1[jj]   = (_Float16)nxf2[jj]; ax1[jj+4] = (_Float16)nxf3[jj];
        }
        half8 wif[4][2];
        #pragma unroll
        for (int nt = 0; nt < 4; ++nt)
            #pragma unroll
            for (int kt = 0; kt < 2; ++kt)
                wif[nt][kt] = *(const half8*)(wih0g + (nt * 128 + j0) * 64 + kt * 32 + quad * 8);
        half8 ah[4];
        #pragma unroll
        for (int kt = 0; kt < 4; ++kt)
            ah[kt] = *(const half8*)(h0b + pbo + hoff[kt]);

        f32x4 acc[4];
        #pragma unroll
        for (int nt = 0; nt < 4; ++nt) {
            f32x4 b = {bias0[nt], bias0[nt], bias0[nt], bias0[nt]};
            acc[nt] = b;
        }
        #pragma unroll
        for (int kt = 0; kt < 4; ++kt)
            #pragma unroll
            for (int nt = 0; nt < 4; ++nt)
                acc[nt] = __builtin_amdgcn_mfma_f32_16x16x32_f16(ah[kt], whh0f[nt][kt], acc[nt], 0, 0, 0);
        #pragma unroll
        for (int kt = 0; kt < 2; ++kt) {
            half8 axk = kt ? ax1 : ax0;
            #pragma unroll
            for (int nt = 0; nt < 4; ++nt)
                acc[nt] = __builtin_amdgcn_mfma_f32_16x16x32_f16(axk, wif[nt][kt], acc[nt], 0, 0, 0);
        }
        {
            int tn = (t + 1 < T_STEPS) ? t + 1 : t;
            const float* xq = xpf + (size_t)tn * (BATCH * DIN);
            nxf0 = *(const f32x4*)(xq);      nxf1 = *(const f32x4*)(xq + 4);
            nxf2 = *(const f32x4*)(xq + 32); nxf3 = *(const f32x4*)(xq + 36);
        }
        #pragma unroll
        for (int i = 0; i < 4; ++i) {
            float ig = sig2(acc[0][i]);
            float fg = sig2(acc[1][i]);
            float gg = tanh2(acc[2][i]);
            float og = sig2(acc[3][i]);
            float c  = fg * c0[i] + ig * gg;
            c0[i] = c;
            h0b[cbo + w0off[i]] = (_Float16)(og * tanh_c(c));
        }
        __syncthreads();

        #pragma unroll
        for (int nt = 0; nt < 4; ++nt) {
            f32x4 b = {bias1[nt], bias1[nt], bias1[nt], bias1[nt]};
            acc[nt] = b;
        }
        #pragma unroll
        for (int kt = 0; kt < 4; ++kt) {
            half8 a0 = *(const half8*)(h0b + cbo + hoff[kt]);
            half8 a1 = *(const half8*)(h1b + pbo + hoff[kt]);
            #pragma unroll
            for (int nt = 0; nt < 4; ++nt)
                acc[nt] = __builtin_amdgcn_mfma_f32_16x16x32_f16(a0, wih1f[nt][kt], acc[nt], 0, 0, 0);
            #pragma unroll
            for (int nt = 0; nt < 4; ++nt) {
                half8 bfr = *(const half8*)(whh1 + nt * 16384 + j0 * 128 + swz[kt]);
                acc[nt] = __builtin_amdgcn_mfma_f32_16x16x32_f16(a1, bfr, acc[nt], 0, 0, 0);
            }
        }
        #pragma unroll
        for (int i = 0; i < 4; ++i) {
            float ig = sig2(acc[0][i]);
            float fg = sig2(acc[1][i]);
            float gg = tanh2(acc[2][i]);
            float og = sig2(acc[3][i]);
            float c  = fg * c1[i] + ig * gg;
            c1[i] = c;
            h1b[cbo + w0off[i]] = (_Float16)(og * tanh_c(c));
        }
        if (w == 7) {
            f32x4 vh = {0.f, 0.f, 0.f, 0.f};
            #pragma unroll
            for (int kt = 0; kt < 4; ++kt) {
                half8 a1 = *(const half8*)(h1b + pbo + hoff[kt]);
                half8 bw = *(const half8*)(woutl + kt * 32 + quad * 8);
                vh = __builtin_amdgcn_mfma_f32_16x16x32_f16(a1, bw, vh, 0, 0, 0);
            }
            if (t > 0 && col == 0) {
                f32x4 vo = {vh[0] + bout, vh[1] + bout, vh[2] + bout, vh[3] + bout};
                *(f32x4*)(out + (size_t)(t - 1) * BATCH + rowbase + quad * 4) = vo;
            }
        }
    }
    __syncthreads();
    if (w == 7) {
        const int fbo = (((T_STEPS - 1) & 1) ^ 1) * 2048;
        f32x4 vh = {0.f, 0.f, 0.f, 0.f};
        #pragma unroll
        for (int kt = 0; kt < 4; ++kt) {
            half8 a1 = *(const half8*)(h1b + fbo + hoff[kt]);
            half8 bw = *(const half8*)(woutl + kt * 32 + quad * 8);
            vh = __builtin_amdgcn_mfma_f32_16x16x32_f16(a1, bw, vh, 0, 0, 0);
        }
        if (col == 0) {
            f32x4 vo = {vh[0] + bout, vh[1] + bout, vh[2] + bout, vh[3] + bout};
            *(f32x4*)(out + (size_t)(T_STEPS - 1) * BATCH + rowbase + quad * 4) = vo;
        }
    }
}

extern "C" void kernel_launch(void* const* d_in, const int* in_sizes, int n_in,
                              void* d_out, int out_size, void* d_ws, size_t ws_size,
                              hipStream_t stream) {
    const float* state = (const float*)d_in[0];
    const float* wih0  = (const float*)d_in[1];
    const float* whh0  = (const float*)d_in[2];
    const float* bih0  = (const float*)d_in[3];
    const float* bhh0  = (const float*)d_in[4];
    const float* wih1  = (const float*)d_in[5];
    const float* whh1  = (const float*)d_in[6];
    const float* bih1  = (const float*)d_in[7];
    const float* bhh1  = (const float*)d_in[8];
    const float* wout  = (const float*)d_in[9];
    const float* bout  = (const float*)d_in[10];
    _Float16* wsh = (_Float16*)d_ws;
    float* outp = (float*)d_out;

    prep_weights<<<896, 256, 0, stream>>>(wih0, whh0, wih1, whh1, wsh);

    if (ws_size >= WS2_TOTAL) {
        prep_state<<<4096, 256, 0, stream>>>(state, wsh + WH_X2);
        lstm_pipe<true><<<32, 512, PIPE_LDS_BYTES, stream>>>(
            state, wsh, bih0, bhh0, bih1, bhh1, wout, bout,
            wsh + WH_SLAB2, (int*)((char*)d_ws + WB_FLAG2), wsh + WH_X2, outp);
    } else if (ws_size >= WS1_TOTAL) {
        lstm_pipe<false><<<32, 512, PIPE_LDS_BYTES, stream>>>(
            state, wsh, bih0, bhh0, bih1, bhh1, wout, bout,
            wsh + WH_SLAB1, (int*)((char*)d_ws + WB_FLAG1), nullptr, outp);
    } else {
        lstm_mono<<<16, 512, MONO_LDS_BYTES, stream>>>(
            state, wsh, bih0, bhh0, bih1, bhh1, wout, bout, outp);
    }
}